// Round 1
// baseline (495.390 us; speedup 1.0000x reference)
//
#include <hip/hip_runtime.h>
#include <math.h>

#define NV 3
#define DIMX 128
#define HD 64
#define NVH 192

__device__ __forceinline__ unsigned fkey(float f){
  unsigned b = __float_as_uint(f);
  return (b & 0x80000000u) ? ~b : (b | 0x80000000u);
}
__device__ __forceinline__ float unkey(unsigned k){
  return __uint_as_float((k & 0x80000000u) ? (k ^ 0x80000000u) : ~k);
}

// ---- CSR build ----
__global__ void k_count(const int* __restrict__ ei, int E, int* __restrict__ cnt){
  int e = blockIdx.x*blockDim.x + threadIdx.x;
  if (e < E){
    int d = ei[E + e];
    atomicAdd(&cnt[d], 1);
  }
}

__global__ void k_dinv(const int* __restrict__ cnt, int N, float* __restrict__ dinv){
  int n = blockIdx.x*blockDim.x + threadIdx.x;
  if (n < N) dinv[n] = rsqrtf((float)(cnt[n] + 1));   // +1 self-loop, deg>=1 always
}

__global__ __launch_bounds__(1024) void k_scan(const int* __restrict__ cnt, int N, int* __restrict__ rowstart){
  __shared__ int sh[1024];
  int t = threadIdx.x;
  int chunk = (N + 1023) >> 10;
  int lo = t*chunk, hi = min(lo+chunk, N);
  int s = 0;
  for (int i = lo; i < hi; ++i) s += cnt[i];
  sh[t] = s; __syncthreads();
  for (int ofs = 1; ofs < 1024; ofs <<= 1){
    int v = (t >= ofs) ? sh[t-ofs] : 0;
    __syncthreads();
    sh[t] += v;
    __syncthreads();
  }
  int run = sh[t] - s;           // exclusive prefix of this thread's chunk
  for (int i = lo; i < hi; ++i){ rowstart[i] = run; run += cnt[i]; }
  if (t == 1023) rowstart[N] = sh[1023];
}

__global__ void k_fill(const int* __restrict__ ei, int E, const int* __restrict__ rowstart,
                       int* __restrict__ fill, int* __restrict__ csr){
  int e = blockIdx.x*blockDim.x + threadIdx.x;
  if (e < E){
    int s = ei[e], d = ei[E + e];
    int pos = rowstart[d] + atomicAdd(&fill[d], 1);
    csr[pos] = s;
  }
}

// ---- per-node linear transform: hs[n, v*64+h] = dinv[n] * sum_d x[n,v,d]*Wv[v,d,h] ----
__global__ __launch_bounds__(256) void k_h(const float* __restrict__ x, const float* __restrict__ Wv,
                                           const float* __restrict__ dinv, float* __restrict__ hs, int N){
  __shared__ float sW[DIMX*HD];     // [d][h]
  __shared__ float sX[32*132];      // [d_local][n] transposed, pad 132
  int v = blockIdx.y;
  int t = threadIdx.x;
  int n_base = blockIdx.x * 128;
  const float* Wg = Wv + v*DIMX*HD;
  #pragma unroll
  for (int k = 0; k < 8; ++k){
    int idx = t*4 + k*1024;
    *(float4*)&sW[idx] = *(const float4*)&Wg[idx];
  }
  int ng = t & 31, hg = t >> 5;     // thread tile: 4 nodes x 8 h
  float acc[4][8];
  #pragma unroll
  for (int i = 0; i < 4; ++i)
    #pragma unroll
    for (int j = 0; j < 8; ++j) acc[i][j] = 0.f;

  int n_s = t >> 1, half = t & 1;
  for (int dc = 0; dc < DIMX; dc += 32){
    __syncthreads();
    int gn = n_base + n_s;
    #pragma unroll
    for (int k = 0; k < 4; ++k){
      float4 xv = make_float4(0.f,0.f,0.f,0.f);
      int d0 = dc + half*16 + k*4;
      if (gn < N) xv = *(const float4*)&x[(size_t)gn*384 + v*128 + d0];
      int dl = half*16 + k*4;
      sX[(dl+0)*132 + n_s] = xv.x;
      sX[(dl+1)*132 + n_s] = xv.y;
      sX[(dl+2)*132 + n_s] = xv.z;
      sX[(dl+3)*132 + n_s] = xv.w;
    }
    __syncthreads();
    #pragma unroll
    for (int d = 0; d < 32; ++d){
      float4 xq = *(float4*)&sX[d*132 + ng*4];
      float4 wa = *(float4*)&sW[(dc+d)*64 + hg*8];
      float4 wb = *(float4*)&sW[(dc+d)*64 + hg*8 + 4];
      float xs[4] = {xq.x, xq.y, xq.z, xq.w};
      float wv[8] = {wa.x, wa.y, wa.z, wa.w, wb.x, wb.y, wb.z, wb.w};
      #pragma unroll
      for (int i = 0; i < 4; ++i)
        #pragma unroll
        for (int j = 0; j < 8; ++j)
          acc[i][j] += xs[i]*wv[j];
    }
  }
  #pragma unroll
  for (int i = 0; i < 4; ++i){
    int n = n_base + ng*4 + i;
    if (n < N){
      float dv = dinv[n];
      float* p = &hs[(size_t)n*NVH + v*64 + hg*8];
      float4 o0 = make_float4(acc[i][0]*dv, acc[i][1]*dv, acc[i][2]*dv, acc[i][3]*dv);
      float4 o1 = make_float4(acc[i][4]*dv, acc[i][5]*dv, acc[i][6]*dv, acc[i][7]*dv);
      *(float4*)p = o0;
      *(float4*)&p[4] = o1;
    }
  }
}

// ---- aggregation (wave per dst node) + relu + node-attention scores ----
__global__ __launch_bounds__(256) void k_agg(const float* __restrict__ hs, const int* __restrict__ rowstart,
                                             const int* __restrict__ csr, const float* __restrict__ dinv,
                                             const float* __restrict__ bv, const float* __restrict__ na_w,
                                             const float* __restrict__ na_b,
                                             float* __restrict__ emb, float* __restrict__ scores, int N){
  int wid = (blockIdx.x*blockDim.x + threadIdx.x) >> 6;
  int lane = threadIdx.x & 63;
  if (wid >= N) return;
  int n = wid;
  const float* hp0 = hs + (size_t)n*NVH;
  float a0 = hp0[lane], a1 = hp0[64+lane], a2 = hp0[128+lane];   // self-loop
  int r0 = rowstart[n], r1 = rowstart[n+1];
  for (int base = r0; base < r1; base += 64){
    int m = r1 - base; if (m > 64) m = 64;
    int sv = (lane < m) ? csr[base + lane] : 0;
    for (int i = 0; i < m; ++i){
      int s = __shfl(sv, i);
      const float* hp = hs + (size_t)s*NVH;
      a0 += hp[lane]; a1 += hp[64+lane]; a2 += hp[128+lane];
    }
  }
  float dv = dinv[n];
  float e0 = fmaxf(a0*dv + bv[lane],      0.f);
  float e1 = fmaxf(a1*dv + bv[64+lane],   0.f);
  float e2 = fmaxf(a2*dv + bv[128+lane],  0.f);
  float* ep = emb + (size_t)n*NVH;
  ep[lane] = e0; ep[64+lane] = e1; ep[128+lane] = e2;
  float w = na_w[lane];
  float s0 = e0*w, s1 = e1*w, s2 = e2*w;
  #pragma unroll
  for (int ofs = 32; ofs >= 1; ofs >>= 1){
    s0 += __shfl_xor(s0, ofs);
    s1 += __shfl_xor(s1, ofs);
    s2 += __shfl_xor(s2, ofs);
  }
  if (lane == 0){
    float nb = na_b[0];
    scores[n] = s0 + nb; scores[N + n] = s1 + nb; scores[2*N + n] = s2 + nb;
  }
}

// ---- global max per view ----
__global__ void k_max(const float* __restrict__ scores, int N, unsigned* __restrict__ maxkey){
  __shared__ float sh[256];
  int v = blockIdx.y;
  const float* sp = scores + (size_t)v*N;
  int base = blockIdx.x*2048 + threadIdx.x;
  float m = -3.0e38f;
  #pragma unroll
  for (int k = 0; k < 8; ++k){
    int i = base + k*256;
    if (i < N) m = fmaxf(m, sp[i]);
  }
  sh[threadIdx.x] = m; __syncthreads();
  for (int ofs = 128; ofs >= 1; ofs >>= 1){
    if (threadIdx.x < ofs) sh[threadIdx.x] = fmaxf(sh[threadIdx.x], sh[threadIdx.x+ofs]);
    __syncthreads();
  }
  if (threadIdx.x == 0) atomicMax(&maxkey[v], fkey(sh[0]));
}

// ---- sum(exp) per view + weighted sum over nodes (for view attention) ----
__global__ __launch_bounds__(256) void k_wsum(const float* __restrict__ emb, const float* __restrict__ scores,
                                              const unsigned* __restrict__ maxkey, float* __restrict__ wsum,
                                              float* __restrict__ sumexp, int N){
  int lane = threadIdx.x & 63;
  int gw = (blockIdx.x*blockDim.x + threadIdx.x) >> 6;
  int nw = (gridDim.x*blockDim.x) >> 6;
  float m0 = unkey(maxkey[0]), m1 = unkey(maxkey[1]), m2 = unkey(maxkey[2]);
  float w0=0.f, w1=0.f, w2=0.f, se0=0.f, se1=0.f, se2=0.f;
  for (int n = gw; n < N; n += nw){
    const float* ep = emb + (size_t)n*NVH;
    float x0 = expf(scores[n]       - m0);
    float x1 = expf(scores[N + n]   - m1);
    float x2 = expf(scores[2*N + n] - m2);
    w0 += ep[lane]*x0; w1 += ep[64+lane]*x1; w2 += ep[128+lane]*x2;
    se0 += x0; se1 += x1; se2 += x2;
  }
  atomicAdd(&wsum[lane],      w0);
  atomicAdd(&wsum[64+lane],   w1);
  atomicAdd(&wsum[128+lane],  w2);
  if (lane == 0){
    atomicAdd(&sumexp[0], se0); atomicAdd(&sumexp[1], se1); atomicAdd(&sumexp[2], se2);
  }
}

// ---- view attention (tiny) ----
__global__ __launch_bounds__(64) void k_view(const float* __restrict__ wsum, const float* __restrict__ sumexp,
                                             const float* __restrict__ va_w1, const float* __restrict__ va_b1,
                                             const float* __restrict__ va_w2, const float* __restrict__ va_b2,
                                             float* __restrict__ g, float* __restrict__ out_vw, int N){
  __shared__ float avg[NV][64];
  __shared__ float z1[NV][32];
  int t = threadIdx.x;
  if (t < 64){
    for (int v = 0; v < NV; ++v) avg[v][t] = wsum[v*64+t] / (sumexp[v] * (float)N);
  }
  __syncthreads();
  if (t < 32){
    for (int v = 0; v < NV; ++v){
      float a = va_b1[t];
      for (int h = 0; h < 64; ++h) a += avg[v][h]*va_w1[h*32 + t];
      z1[v][t] = tanhf(a);
    }
  }
  __syncthreads();
  if (t == 0){
    float vs[NV];
    for (int v = 0; v < NV; ++v){
      float a = va_b2[0];
      for (int j = 0; j < 32; ++j) a += z1[v][j]*va_w2[j];
      vs[v] = a;
    }
    float m = fmaxf(vs[0], fmaxf(vs[1], vs[2]));
    float e0 = expf(vs[0]-m), e1 = expf(vs[1]-m), e2 = expf(vs[2]-m);
    float inv = 1.f/(e0+e1+e2);
    float vw0 = e0*inv, vw1 = e1*inv, vw2 = e2*inv;
    out_vw[0] = vw0; out_vw[1] = vw1; out_vw[2] = vw2;
    g[0] = vw0/sumexp[0]; g[1] = vw1/sumexp[1]; g[2] = vw2/sumexp[2];
  }
}

// ---- fused output + classifier + log_softmax (wave per node) ----
__global__ __launch_bounds__(256) void k_fused(const float* __restrict__ emb, const float* __restrict__ scores,
                                               const unsigned* __restrict__ maxkey, const float* __restrict__ g,
                                               const float* __restrict__ cls_w, const float* __restrict__ cls_b,
                                               float* __restrict__ out, int N){
  int wid = (blockIdx.x*blockDim.x + threadIdx.x) >> 6;
  int lane = threadIdx.x & 63;
  if (wid >= N) return;
  int n = wid;
  float m0 = unkey(maxkey[0]), m1 = unkey(maxkey[1]), m2 = unkey(maxkey[2]);
  float w0 = expf(scores[n]       - m0)*g[0];
  float w1 = expf(scores[N + n]   - m1)*g[1];
  float w2 = expf(scores[2*N + n] - m2)*g[2];
  const float* ep = emb + (size_t)n*NVH;
  float fu = ep[lane]*w0 + ep[64+lane]*w1 + ep[128+lane]*w2;
  out[(size_t)2*N + (size_t)n*64 + lane] = fu;
  float c0 = fu*cls_w[lane*2 + 0];
  float c1 = fu*cls_w[lane*2 + 1];
  #pragma unroll
  for (int ofs = 32; ofs >= 1; ofs >>= 1){
    c0 += __shfl_xor(c0, ofs);
    c1 += __shfl_xor(c1, ofs);
  }
  if (lane == 0){
    float l0 = c0 + cls_b[0], l1 = c1 + cls_b[1];
    float m = fmaxf(l0, l1);
    float lse = m + logf(expf(l0-m) + expf(l1-m));
    out[(size_t)n*2]     = l0 - lse;
    out[(size_t)n*2 + 1] = l1 - lse;
  }
}

extern "C" void kernel_launch(void* const* d_in, const int* in_sizes, int n_in,
                              void* d_out, int out_size, void* d_ws, size_t ws_size,
                              hipStream_t stream){
  const float* x     = (const float*)d_in[0];
  const int*   ei    = (const int*)d_in[1];
  const float* Wv    = (const float*)d_in[2];
  const float* bv    = (const float*)d_in[3];
  const float* na_w  = (const float*)d_in[4];
  const float* na_b  = (const float*)d_in[5];
  const float* va_w1 = (const float*)d_in[6];
  const float* va_b1 = (const float*)d_in[7];
  const float* va_w2 = (const float*)d_in[8];
  const float* va_b2 = (const float*)d_in[9];
  const float* cls_w = (const float*)d_in[10];
  const float* cls_b = (const float*)d_in[11];
  int N = in_sizes[0] / (NV*DIMX);
  int E = in_sizes[1] / 2;
  float* out = (float*)d_out;

  char* wptr = (char*)d_ws;
  size_t off = 0;
  auto alloc = [&](size_t bytes){ void* p = wptr + off; off += (bytes + 255) & ~255ull; return p; };
  float*    hs       = (float*)alloc((size_t)N*NVH*4);
  float*    emb      = (float*)alloc((size_t)N*NVH*4);
  int*      csr      = (int*)alloc((size_t)E*4);
  int*      cnt      = (int*)alloc((size_t)N*4);
  int*      rowstart = (int*)alloc((size_t)(N+1)*4);
  int*      fill     = (int*)alloc((size_t)N*4);
  float*    dinv     = (float*)alloc((size_t)N*4);
  float*    scores   = (float*)alloc((size_t)3*N*4);
  unsigned* maxkey   = (unsigned*)alloc(3*4);
  float*    sumexp   = (float*)alloc(3*4);
  float*    wsum     = (float*)alloc(192*4);
  float*    g        = (float*)alloc(3*4);

  hipMemsetAsync(cnt,    0, (size_t)N*4, stream);
  hipMemsetAsync(fill,   0, (size_t)N*4, stream);
  hipMemsetAsync(maxkey, 0, 3*4, stream);
  hipMemsetAsync(sumexp, 0, 3*4, stream);
  hipMemsetAsync(wsum,   0, 192*4, stream);

  k_count<<<(E+255)/256, 256, 0, stream>>>(ei, E, cnt);
  k_dinv <<<(N+255)/256, 256, 0, stream>>>(cnt, N, dinv);
  k_scan <<<1, 1024, 0, stream>>>(cnt, N, rowstart);
  k_fill <<<(E+255)/256, 256, 0, stream>>>(ei, E, rowstart, fill, csr);
  dim3 gh((N+127)/128, NV);
  k_h    <<<gh, 256, 0, stream>>>(x, Wv, dinv, hs, N);
  k_agg  <<<(N*64+255)/256, 256, 0, stream>>>(hs, rowstart, csr, dinv, bv, na_w, na_b, emb, scores, N);
  dim3 gm((N+2047)/2048, NV);
  k_max  <<<gm, 256, 0, stream>>>(scores, N, maxkey);
  k_wsum <<<1024, 256, 0, stream>>>(emb, scores, maxkey, wsum, sumexp, N);
  k_view <<<1, 64, 0, stream>>>(wsum, sumexp, va_w1, va_b1, va_w2, va_b2, g,
                                out + (size_t)2*N + (size_t)N*64, N);
  k_fused<<<(N*64+255)/256, 256, 0, stream>>>(emb, scores, maxkey, g, cls_w, cls_b, out, N);
}

// Round 2
// 355.763 us; speedup vs baseline: 1.3925x; 1.3925x over previous
//
#include <hip/hip_runtime.h>
#include <math.h>

#define NV 3
#define DIMX 128
#define HD 64
#define NVH 192

__device__ __forceinline__ unsigned fkey(float f){
  unsigned b = __float_as_uint(f);
  return (b & 0x80000000u) ? ~b : (b | 0x80000000u);
}
__device__ __forceinline__ float unkey(unsigned k){
  return __uint_as_float((k & 0x80000000u) ? (k ^ 0x80000000u) : ~k);
}

// ---- CSR build ----
__global__ void k_count(const int* __restrict__ ei, int E, int* __restrict__ cnt){
  int e = blockIdx.x*blockDim.x + threadIdx.x;
  if (e < E){
    int d = ei[E + e];
    atomicAdd(&cnt[d], 1);
  }
}

__global__ void k_dinv(const int* __restrict__ cnt, int N, float* __restrict__ dinv){
  int n = blockIdx.x*blockDim.x + threadIdx.x;
  if (n < N) dinv[n] = rsqrtf((float)(cnt[n] + 1));   // +1 self-loop, deg>=1 always
}

__global__ __launch_bounds__(1024) void k_scan(const int* __restrict__ cnt, int N, int* __restrict__ rowstart){
  __shared__ int sh[1024];
  int t = threadIdx.x;
  int chunk = (N + 1023) >> 10;
  int lo = t*chunk, hi = min(lo+chunk, N);
  int s = 0;
  for (int i = lo; i < hi; ++i) s += cnt[i];
  sh[t] = s; __syncthreads();
  for (int ofs = 1; ofs < 1024; ofs <<= 1){
    int v = (t >= ofs) ? sh[t-ofs] : 0;
    __syncthreads();
    sh[t] += v;
    __syncthreads();
  }
  int run = sh[t] - s;           // exclusive prefix of this thread's chunk
  for (int i = lo; i < hi; ++i){ rowstart[i] = run; run += cnt[i]; }
  if (t == 1023) rowstart[N] = sh[1023];
}

__global__ void k_fill(const int* __restrict__ ei, int E, const int* __restrict__ rowstart,
                       int* __restrict__ fill, int* __restrict__ csr){
  int e = blockIdx.x*blockDim.x + threadIdx.x;
  if (e < E){
    int s = ei[e], d = ei[E + e];
    int pos = rowstart[d] + atomicAdd(&fill[d], 1);
    csr[pos] = s;
  }
}

// ---- per-node linear transform: hs[n, v*64+h] = dinv[n] * sum_d x[n,v,d]*Wv[v,d,h] ----
__global__ __launch_bounds__(256) void k_h(const float* __restrict__ x, const float* __restrict__ Wv,
                                           const float* __restrict__ dinv, float* __restrict__ hs, int N){
  __shared__ float sW[DIMX*HD];     // [d][h]
  __shared__ float sX[32*132];      // [d_local][n] transposed, pad 132
  int v = blockIdx.y;
  int t = threadIdx.x;
  int n_base = blockIdx.x * 128;
  const float* Wg = Wv + v*DIMX*HD;
  #pragma unroll
  for (int k = 0; k < 8; ++k){
    int idx = t*4 + k*1024;
    *(float4*)&sW[idx] = *(const float4*)&Wg[idx];
  }
  int ng = t & 31, hg = t >> 5;     // thread tile: 4 nodes x 8 h
  float acc[4][8];
  #pragma unroll
  for (int i = 0; i < 4; ++i)
    #pragma unroll
    for (int j = 0; j < 8; ++j) acc[i][j] = 0.f;

  int n_s = t >> 1, half = t & 1;
  for (int dc = 0; dc < DIMX; dc += 32){
    __syncthreads();
    int gn = n_base + n_s;
    #pragma unroll
    for (int k = 0; k < 4; ++k){
      float4 xv = make_float4(0.f,0.f,0.f,0.f);
      int d0 = dc + half*16 + k*4;
      if (gn < N) xv = *(const float4*)&x[(size_t)gn*384 + v*128 + d0];
      int dl = half*16 + k*4;
      sX[(dl+0)*132 + n_s] = xv.x;
      sX[(dl+1)*132 + n_s] = xv.y;
      sX[(dl+2)*132 + n_s] = xv.z;
      sX[(dl+3)*132 + n_s] = xv.w;
    }
    __syncthreads();
    #pragma unroll
    for (int d = 0; d < 32; ++d){
      float4 xq = *(float4*)&sX[d*132 + ng*4];
      float4 wa = *(float4*)&sW[(dc+d)*64 + hg*8];
      float4 wb = *(float4*)&sW[(dc+d)*64 + hg*8 + 4];
      float xs[4] = {xq.x, xq.y, xq.z, xq.w};
      float wv[8] = {wa.x, wa.y, wa.z, wa.w, wb.x, wb.y, wb.z, wb.w};
      #pragma unroll
      for (int i = 0; i < 4; ++i)
        #pragma unroll
        for (int j = 0; j < 8; ++j)
          acc[i][j] += xs[i]*wv[j];
    }
  }
  #pragma unroll
  for (int i = 0; i < 4; ++i){
    int n = n_base + ng*4 + i;
    if (n < N){
      float dv = dinv[n];
      float* p = &hs[(size_t)n*NVH + v*64 + hg*8];
      float4 o0 = make_float4(acc[i][0]*dv, acc[i][1]*dv, acc[i][2]*dv, acc[i][3]*dv);
      float4 o1 = make_float4(acc[i][4]*dv, acc[i][5]*dv, acc[i][6]*dv, acc[i][7]*dv);
      *(float4*)p = o0;
      *(float4*)&p[4] = o1;
    }
  }
}

// ---- aggregation (wave per dst node) + relu + node-attention scores ----
__global__ __launch_bounds__(256) void k_agg(const float* __restrict__ hs, const int* __restrict__ rowstart,
                                             const int* __restrict__ csr, const float* __restrict__ dinv,
                                             const float* __restrict__ bv, const float* __restrict__ na_w,
                                             const float* __restrict__ na_b,
                                             float* __restrict__ emb, float* __restrict__ scores, int N){
  int wid = (blockIdx.x*blockDim.x + threadIdx.x) >> 6;
  int lane = threadIdx.x & 63;
  if (wid >= N) return;
  int n = wid;
  const float* hp0 = hs + (size_t)n*NVH;
  float a0 = hp0[lane], a1 = hp0[64+lane], a2 = hp0[128+lane];   // self-loop
  int r0 = rowstart[n], r1 = rowstart[n+1];
  for (int base = r0; base < r1; base += 64){
    int m = r1 - base; if (m > 64) m = 64;
    int sv = (lane < m) ? csr[base + lane] : 0;
    for (int i = 0; i < m; ++i){
      int s = __shfl(sv, i);
      const float* hp = hs + (size_t)s*NVH;
      a0 += hp[lane]; a1 += hp[64+lane]; a2 += hp[128+lane];
    }
  }
  float dv = dinv[n];
  float e0 = fmaxf(a0*dv + bv[lane],      0.f);
  float e1 = fmaxf(a1*dv + bv[64+lane],   0.f);
  float e2 = fmaxf(a2*dv + bv[128+lane],  0.f);
  float* ep = emb + (size_t)n*NVH;
  ep[lane] = e0; ep[64+lane] = e1; ep[128+lane] = e2;
  float w = na_w[lane];
  float s0 = e0*w, s1 = e1*w, s2 = e2*w;
  #pragma unroll
  for (int ofs = 32; ofs >= 1; ofs >>= 1){
    s0 += __shfl_xor(s0, ofs);
    s1 += __shfl_xor(s1, ofs);
    s2 += __shfl_xor(s2, ofs);
  }
  if (lane == 0){
    float nb = na_b[0];
    scores[n] = s0 + nb; scores[N + n] = s1 + nb; scores[2*N + n] = s2 + nb;
  }
}

// ---- global max per view ----
__global__ void k_max(const float* __restrict__ scores, int N, unsigned* __restrict__ maxkey){
  __shared__ float sh[256];
  int v = blockIdx.y;
  const float* sp = scores + (size_t)v*N;
  int base = blockIdx.x*2048 + threadIdx.x;
  float m = -3.0e38f;
  #pragma unroll
  for (int k = 0; k < 8; ++k){
    int i = base + k*256;
    if (i < N) m = fmaxf(m, sp[i]);
  }
  sh[threadIdx.x] = m; __syncthreads();
  for (int ofs = 128; ofs >= 1; ofs >>= 1){
    if (threadIdx.x < ofs) sh[threadIdx.x] = fmaxf(sh[threadIdx.x], sh[threadIdx.x+ofs]);
    __syncthreads();
  }
  if (threadIdx.x == 0) atomicMax(&maxkey[v], fkey(sh[0]));
}

// ---- sum(exp) per view + weighted sum over nodes, hierarchical (LDS -> 1 atomic/block) ----
__global__ __launch_bounds__(256) void k_wsum(const float* __restrict__ emb, const float* __restrict__ scores,
                                              const unsigned* __restrict__ maxkey, float* __restrict__ wsum,
                                              float* __restrict__ sumexp, int N){
  __shared__ float shw[4][NVH];   // per-wave partials
  __shared__ float shse[4][4];
  int t = threadIdx.x;
  int lane = t & 63;
  int wv = t >> 6;
  int gw = (blockIdx.x*blockDim.x + t) >> 6;
  int nw = (gridDim.x*blockDim.x) >> 6;
  float m0 = unkey(maxkey[0]), m1 = unkey(maxkey[1]), m2 = unkey(maxkey[2]);
  float w0=0.f, w1=0.f, w2=0.f, se0=0.f, se1=0.f, se2=0.f;
  for (int n = gw; n < N; n += nw){
    const float* ep = emb + (size_t)n*NVH;
    float x0 = expf(scores[n]       - m0);
    float x1 = expf(scores[N + n]   - m1);
    float x2 = expf(scores[2*N + n] - m2);
    w0 += ep[lane]*x0; w1 += ep[64+lane]*x1; w2 += ep[128+lane]*x2;
    se0 += x0; se1 += x1; se2 += x2;
  }
  shw[wv][lane]       = w0;
  shw[wv][64+lane]    = w1;
  shw[wv][128+lane]   = w2;
  // wave-reduce the scalar sums, lane 0 stages them
  #pragma unroll
  for (int ofs = 32; ofs >= 1; ofs >>= 1){
    se0 += __shfl_xor(se0, ofs);
    se1 += __shfl_xor(se1, ofs);
    se2 += __shfl_xor(se2, ofs);
  }
  if (lane == 0){ shse[wv][0] = se0; shse[wv][1] = se1; shse[wv][2] = se2; }
  __syncthreads();
  if (t < NVH){
    float s = shw[0][t] + shw[1][t] + shw[2][t] + shw[3][t];
    atomicAdd(&wsum[t], s);
  } else if (t >= NVH && t < NVH+3){
    int v = t - NVH;
    float s = shse[0][v] + shse[1][v] + shse[2][v] + shse[3][v];
    atomicAdd(&sumexp[v], s);
  }
}

// ---- view attention (tiny) ----
__global__ __launch_bounds__(64) void k_view(const float* __restrict__ wsum, const float* __restrict__ sumexp,
                                             const float* __restrict__ va_w1, const float* __restrict__ va_b1,
                                             const float* __restrict__ va_w2, const float* __restrict__ va_b2,
                                             float* __restrict__ g, float* __restrict__ out_vw, int N){
  __shared__ float avg[NV][64];
  __shared__ float z1[NV][32];
  int t = threadIdx.x;
  if (t < 64){
    for (int v = 0; v < NV; ++v) avg[v][t] = wsum[v*64+t] / (sumexp[v] * (float)N);
  }
  __syncthreads();
  if (t < 32){
    for (int v = 0; v < NV; ++v){
      float a = va_b1[t];
      for (int h = 0; h < 64; ++h) a += avg[v][h]*va_w1[h*32 + t];
      z1[v][t] = tanhf(a);
    }
  }
  __syncthreads();
  if (t == 0){
    float vs[NV];
    for (int v = 0; v < NV; ++v){
      float a = va_b2[0];
      for (int j = 0; j < 32; ++j) a += z1[v][j]*va_w2[j];
      vs[v] = a;
    }
    float m = fmaxf(vs[0], fmaxf(vs[1], vs[2]));
    float e0 = expf(vs[0]-m), e1 = expf(vs[1]-m), e2 = expf(vs[2]-m);
    float inv = 1.f/(e0+e1+e2);
    float vw0 = e0*inv, vw1 = e1*inv, vw2 = e2*inv;
    out_vw[0] = vw0; out_vw[1] = vw1; out_vw[2] = vw2;
    g[0] = vw0/sumexp[0]; g[1] = vw1/sumexp[1]; g[2] = vw2/sumexp[2];
  }
}

// ---- fused output + classifier + log_softmax (wave per node) ----
__global__ __launch_bounds__(256) void k_fused(const float* __restrict__ emb, const float* __restrict__ scores,
                                               const unsigned* __restrict__ maxkey, const float* __restrict__ g,
                                               const float* __restrict__ cls_w, const float* __restrict__ cls_b,
                                               float* __restrict__ out, int N){
  int wid = (blockIdx.x*blockDim.x + threadIdx.x) >> 6;
  int lane = threadIdx.x & 63;
  if (wid >= N) return;
  int n = wid;
  float m0 = unkey(maxkey[0]), m1 = unkey(maxkey[1]), m2 = unkey(maxkey[2]);
  float w0 = expf(scores[n]       - m0)*g[0];
  float w1 = expf(scores[N + n]   - m1)*g[1];
  float w2 = expf(scores[2*N + n] - m2)*g[2];
  const float* ep = emb + (size_t)n*NVH;
  float fu = ep[lane]*w0 + ep[64+lane]*w1 + ep[128+lane]*w2;
  out[(size_t)2*N + (size_t)n*64 + lane] = fu;
  float c0 = fu*cls_w[lane*2 + 0];
  float c1 = fu*cls_w[lane*2 + 1];
  #pragma unroll
  for (int ofs = 32; ofs >= 1; ofs >>= 1){
    c0 += __shfl_xor(c0, ofs);
    c1 += __shfl_xor(c1, ofs);
  }
  if (lane == 0){
    float l0 = c0 + cls_b[0], l1 = c1 + cls_b[1];
    float m = fmaxf(l0, l1);
    float lse = m + logf(expf(l0-m) + expf(l1-m));
    out[(size_t)n*2]     = l0 - lse;
    out[(size_t)n*2 + 1] = l1 - lse;
  }
}

extern "C" void kernel_launch(void* const* d_in, const int* in_sizes, int n_in,
                              void* d_out, int out_size, void* d_ws, size_t ws_size,
                              hipStream_t stream){
  const float* x     = (const float*)d_in[0];
  const int*   ei    = (const int*)d_in[1];
  const float* Wv    = (const float*)d_in[2];
  const float* bv    = (const float*)d_in[3];
  const float* na_w  = (const float*)d_in[4];
  const float* na_b  = (const float*)d_in[5];
  const float* va_w1 = (const float*)d_in[6];
  const float* va_b1 = (const float*)d_in[7];
  const float* va_w2 = (const float*)d_in[8];
  const float* va_b2 = (const float*)d_in[9];
  const float* cls_w = (const float*)d_in[10];
  const float* cls_b = (const float*)d_in[11];
  int N = in_sizes[0] / (NV*DIMX);
  int E = in_sizes[1] / 2;
  float* out = (float*)d_out;

  char* wptr = (char*)d_ws;
  size_t off = 0;
  auto alloc = [&](size_t bytes){ void* p = wptr + off; off += (bytes + 255) & ~255ull; return p; };
  float*    hs       = (float*)alloc((size_t)N*NVH*4);
  float*    emb      = (float*)alloc((size_t)N*NVH*4);
  int*      csr      = (int*)alloc((size_t)E*4);
  int*      cnt      = (int*)alloc((size_t)N*4);
  int*      rowstart = (int*)alloc((size_t)(N+1)*4);
  int*      fill     = (int*)alloc((size_t)N*4);
  float*    dinv     = (float*)alloc((size_t)N*4);
  float*    scores   = (float*)alloc((size_t)3*N*4);
  unsigned* maxkey   = (unsigned*)alloc(3*4);
  float*    sumexp   = (float*)alloc(3*4);
  float*    wsum     = (float*)alloc(192*4);
  float*    g        = (float*)alloc(3*4);

  hipMemsetAsync(cnt,    0, (size_t)N*4, stream);
  hipMemsetAsync(fill,   0, (size_t)N*4, stream);
  hipMemsetAsync(maxkey, 0, 3*4, stream);
  hipMemsetAsync(sumexp, 0, 3*4, stream);
  hipMemsetAsync(wsum,   0, 192*4, stream);

  k_count<<<(E+255)/256, 256, 0, stream>>>(ei, E, cnt);
  k_dinv <<<(N+255)/256, 256, 0, stream>>>(cnt, N, dinv);
  k_scan <<<1, 1024, 0, stream>>>(cnt, N, rowstart);
  k_fill <<<(E+255)/256, 256, 0, stream>>>(ei, E, rowstart, fill, csr);
  dim3 gh((N+127)/128, NV);
  k_h    <<<gh, 256, 0, stream>>>(x, Wv, dinv, hs, N);
  k_agg  <<<(N*64+255)/256, 256, 0, stream>>>(hs, rowstart, csr, dinv, bv, na_w, na_b, emb, scores, N);
  dim3 gm((N+2047)/2048, NV);
  k_max  <<<gm, 256, 0, stream>>>(scores, N, maxkey);
  k_wsum <<<304, 256, 0, stream>>>(emb, scores, maxkey, wsum, sumexp, N);
  k_view <<<1, 64, 0, stream>>>(wsum, sumexp, va_w1, va_b1, va_w2, va_b2, g,
                                out + (size_t)2*N + (size_t)N*64, N);
  k_fused<<<(N*64+255)/256, 256, 0, stream>>>(emb, scores, maxkey, g, cls_w, cls_b, out, N);
}

// Round 3
// 264.115 us; speedup vs baseline: 1.8757x; 1.3470x over previous
//
#include <hip/hip_runtime.h>
#include <math.h>

#define NV 3
#define DIMX 128
#define HD 64
#define NVH 192
#define TS 1024

typedef unsigned int uint32;
typedef unsigned short ushort16;

__device__ __forceinline__ unsigned fkey(float f){
  unsigned b = __float_as_uint(f);
  return (b & 0x80000000u) ? ~b : (b | 0x80000000u);
}
__device__ __forceinline__ float unkey(unsigned k){
  return __uint_as_float((k & 0x80000000u) ? (k ^ 0x80000000u) : ~k);
}
__device__ __forceinline__ uint32 bf16rne(float f){
  uint32 u = __float_as_uint(f);
  return (u + 0x7fffu + ((u >> 16) & 1u)) >> 16;
}
__device__ __forceinline__ float bflo(uint32 p){ return __uint_as_float(p << 16); }
__device__ __forceinline__ float bfhi(uint32 p){ return __uint_as_float(p & 0xffff0000u); }
__device__ __forceinline__ float bfus(uint32 q){ return __uint_as_float(q << 16); }

// ---- CSR build ----
__global__ void k_count(const int* __restrict__ ei, int E, int* __restrict__ cnt){
  int e = blockIdx.x*blockDim.x + threadIdx.x;
  if (e < E){
    int d = ei[E + e];
    atomicAdd(&cnt[d], 1);
  }
}

__global__ void k_dinv(const int* __restrict__ cnt, int N, float* __restrict__ dinv){
  int n = blockIdx.x*blockDim.x + threadIdx.x;
  if (n < N) dinv[n] = rsqrtf((float)(cnt[n] + 1));   // +1 self-loop
}

// ---- 3-phase coalesced exclusive scan of cnt -> rowstart ----
__global__ __launch_bounds__(256) void k_scanA(const int* __restrict__ cnt, int N, int* __restrict__ bsum){
  __shared__ int sh[256];
  int b = blockIdx.x, t = threadIdx.x;
  int base = b*TS + t*4;
  int s = 0;
  #pragma unroll
  for (int k = 0; k < 4; ++k){ int i = base + k; if (i < N) s += cnt[i]; }
  sh[t] = s; __syncthreads();
  for (int ofs = 128; ofs >= 1; ofs >>= 1){
    if (t < ofs) sh[t] += sh[t+ofs];
    __syncthreads();
  }
  if (t == 0) bsum[b] = sh[0];
}

__global__ void k_scanB(const int* __restrict__ bsum, int NB, int* __restrict__ boff,
                        int* __restrict__ rowstart, int N){
  if (threadIdx.x == 0){
    int run = 0;
    for (int b = 0; b < NB; ++b){ boff[b] = run; run += bsum[b]; }
    rowstart[N] = run;
  }
}

__global__ __launch_bounds__(256) void k_scanC(const int* __restrict__ cnt, int N,
                                               const int* __restrict__ boff, int* __restrict__ rowstart){
  __shared__ int sh[256];
  int b = blockIdx.x, t = threadIdx.x;
  int base = b*TS + t*4;
  int c[4]; int s = 0;
  #pragma unroll
  for (int k = 0; k < 4; ++k){ int i = base + k; c[k] = (i < N) ? cnt[i] : 0; s += c[k]; }
  sh[t] = s; __syncthreads();
  for (int ofs = 1; ofs < 256; ofs <<= 1){
    int v = (t >= ofs) ? sh[t-ofs] : 0;
    __syncthreads();
    sh[t] += v;
    __syncthreads();
  }
  int run = boff[b] + sh[t] - s;     // exclusive prefix for this thread's 4 elems
  #pragma unroll
  for (int k = 0; k < 4; ++k){ int i = base + k; if (i < N){ rowstart[i] = run; run += c[k]; } }
}

__global__ void k_fill(const int* __restrict__ ei, int E, const int* __restrict__ rowstart,
                       int* __restrict__ fill, int* __restrict__ csr){
  int e = blockIdx.x*blockDim.x + threadIdx.x;
  if (e < E){
    int s = ei[e], d = ei[E + e];
    int pos = rowstart[d] + atomicAdd(&fill[d], 1);
    csr[pos] = s;
  }
}

// ---- per-node linear transform: hs[n, v*64+h] = dinv[n] * sum_d x[n,v,d]*Wv[v,d,h] ----
__global__ __launch_bounds__(256) void k_h(const float* __restrict__ x, const float* __restrict__ Wv,
                                           const float* __restrict__ dinv, float* __restrict__ hs, int N){
  __shared__ float sW[DIMX*HD];     // [d][h]
  __shared__ float sX[32*132];      // [d_local][n] transposed, pad 132
  int v = blockIdx.y;
  int t = threadIdx.x;
  int n_base = blockIdx.x * 128;
  const float* Wg = Wv + v*DIMX*HD;
  #pragma unroll
  for (int k = 0; k < 8; ++k){
    int idx = t*4 + k*1024;
    *(float4*)&sW[idx] = *(const float4*)&Wg[idx];
  }
  int ng = t & 31, hg = t >> 5;     // thread tile: 4 nodes x 8 h
  float acc[4][8];
  #pragma unroll
  for (int i = 0; i < 4; ++i)
    #pragma unroll
    for (int j = 0; j < 8; ++j) acc[i][j] = 0.f;

  int n_s = t >> 1, half = t & 1;
  for (int dc = 0; dc < DIMX; dc += 32){
    __syncthreads();
    int gn = n_base + n_s;
    #pragma unroll
    for (int k = 0; k < 4; ++k){
      float4 xv = make_float4(0.f,0.f,0.f,0.f);
      int d0 = dc + half*16 + k*4;
      if (gn < N) xv = *(const float4*)&x[(size_t)gn*384 + v*128 + d0];
      int dl = half*16 + k*4;
      sX[(dl+0)*132 + n_s] = xv.x;
      sX[(dl+1)*132 + n_s] = xv.y;
      sX[(dl+2)*132 + n_s] = xv.z;
      sX[(dl+3)*132 + n_s] = xv.w;
    }
    __syncthreads();
    #pragma unroll
    for (int d = 0; d < 32; ++d){
      float4 xq = *(float4*)&sX[d*132 + ng*4];
      float4 wa = *(float4*)&sW[(dc+d)*64 + hg*8];
      float4 wb = *(float4*)&sW[(dc+d)*64 + hg*8 + 4];
      float xs[4] = {xq.x, xq.y, xq.z, xq.w};
      float wv[8] = {wa.x, wa.y, wa.z, wa.w, wb.x, wb.y, wb.z, wb.w};
      #pragma unroll
      for (int i = 0; i < 4; ++i)
        #pragma unroll
        for (int j = 0; j < 8; ++j)
          acc[i][j] += xs[i]*wv[j];
    }
  }
  #pragma unroll
  for (int i = 0; i < 4; ++i){
    int n = n_base + ng*4 + i;
    if (n < N){
      float dv = dinv[n];
      float* p = &hs[(size_t)n*NVH + v*64 + hg*8];
      float4 o0 = make_float4(acc[i][0]*dv, acc[i][1]*dv, acc[i][2]*dv, acc[i][3]*dv);
      float4 o1 = make_float4(acc[i][4]*dv, acc[i][5]*dv, acc[i][6]*dv, acc[i][7]*dv);
      *(float4*)p = o0;
      *(float4*)&p[4] = o1;
    }
  }
}

// ---- pack hs (fp32) -> h01 (bf16x2 views 0,1) + h2 (bf16 view 2) ----
__global__ __launch_bounds__(256) void k_pack(const float* __restrict__ hs, uint32* __restrict__ h01,
                                              ushort16* __restrict__ h2, int NH){
  int i = blockIdx.x*blockDim.x + threadIdx.x;
  if (i >= NH) return;
  int n = i >> 6, h = i & 63;
  const float* hp = hs + (size_t)n*NVH;
  uint32 a = bf16rne(hp[h]);
  uint32 b = bf16rne(hp[64+h]);
  uint32 c = bf16rne(hp[128+h]);
  h01[i] = a | (b << 16);
  h2[i]  = (ushort16)c;
}

// ---- aggregation (wave per dst node, bf16 gather) + relu + node-attention scores ----
__global__ __launch_bounds__(256) void k_agg(const uint32* __restrict__ h01, const ushort16* __restrict__ h2,
                                             const int* __restrict__ rowstart, const int* __restrict__ csr,
                                             const float* __restrict__ dinv, const float* __restrict__ bv,
                                             const float* __restrict__ na_w, const float* __restrict__ na_b,
                                             float* __restrict__ emb, float* __restrict__ scores, int N){
  int wid = (blockIdx.x*blockDim.x + threadIdx.x) >> 6;
  int lane = threadIdx.x & 63;
  if (wid >= N) return;
  int n = wid;
  // self-loop
  uint32 ps = h01[(size_t)n*64 + lane];
  float a0 = bflo(ps), a1 = bfhi(ps), a2 = bfus(h2[(size_t)n*64 + lane]);
  int r0 = rowstart[n], r1 = rowstart[n+1];
  int i = r0;
  for (; i + 3 < r1; i += 4){
    int s0 = csr[i], s1 = csr[i+1], s2 = csr[i+2], s3 = csr[i+3];
    uint32 pa = h01[(size_t)s0*64 + lane];
    uint32 pb = h01[(size_t)s1*64 + lane];
    uint32 pc = h01[(size_t)s2*64 + lane];
    uint32 pd = h01[(size_t)s3*64 + lane];
    uint32 qa = h2[(size_t)s0*64 + lane];
    uint32 qb = h2[(size_t)s1*64 + lane];
    uint32 qc = h2[(size_t)s2*64 + lane];
    uint32 qd = h2[(size_t)s3*64 + lane];
    a0 += bflo(pa) + bflo(pb) + bflo(pc) + bflo(pd);
    a1 += bfhi(pa) + bfhi(pb) + bfhi(pc) + bfhi(pd);
    a2 += bfus(qa) + bfus(qb) + bfus(qc) + bfus(qd);
  }
  for (; i < r1; ++i){
    int s = csr[i];
    uint32 p = h01[(size_t)s*64 + lane];
    a0 += bflo(p); a1 += bfhi(p); a2 += bfus(h2[(size_t)s*64 + lane]);
  }
  float dv = dinv[n];
  float e0 = fmaxf(a0*dv + bv[lane],      0.f);
  float e1 = fmaxf(a1*dv + bv[64+lane],   0.f);
  float e2 = fmaxf(a2*dv + bv[128+lane],  0.f);
  float* ep = emb + (size_t)n*NVH;
  ep[lane] = e0; ep[64+lane] = e1; ep[128+lane] = e2;
  float w = na_w[lane];
  float s0 = e0*w, s1 = e1*w, s2 = e2*w;
  #pragma unroll
  for (int ofs = 32; ofs >= 1; ofs >>= 1){
    s0 += __shfl_xor(s0, ofs);
    s1 += __shfl_xor(s1, ofs);
    s2 += __shfl_xor(s2, ofs);
  }
  if (lane == 0){
    float nb = na_b[0];
    scores[n] = s0 + nb; scores[N + n] = s1 + nb; scores[2*N + n] = s2 + nb;
  }
}

// ---- global max per view ----
__global__ void k_max(const float* __restrict__ scores, int N, unsigned* __restrict__ maxkey){
  __shared__ float sh[256];
  int v = blockIdx.y;
  const float* sp = scores + (size_t)v*N;
  int base = blockIdx.x*2048 + threadIdx.x;
  float m = -3.0e38f;
  #pragma unroll
  for (int k = 0; k < 8; ++k){
    int i = base + k*256;
    if (i < N) m = fmaxf(m, sp[i]);
  }
  sh[threadIdx.x] = m; __syncthreads();
  for (int ofs = 128; ofs >= 1; ofs >>= 1){
    if (threadIdx.x < ofs) sh[threadIdx.x] = fmaxf(sh[threadIdx.x], sh[threadIdx.x+ofs]);
    __syncthreads();
  }
  if (threadIdx.x == 0) atomicMax(&maxkey[v], fkey(sh[0]));
}

// ---- sum(exp) per view + weighted sum over nodes, hierarchical ----
__global__ __launch_bounds__(256) void k_wsum(const float* __restrict__ emb, const float* __restrict__ scores,
                                              const unsigned* __restrict__ maxkey, float* __restrict__ wsum,
                                              float* __restrict__ sumexp, int N){
  __shared__ float shw[4][NVH];
  __shared__ float shse[4][4];
  int t = threadIdx.x;
  int lane = t & 63;
  int wv = t >> 6;
  int gw = (blockIdx.x*blockDim.x + t) >> 6;
  int nw = (gridDim.x*blockDim.x) >> 6;
  float m0 = unkey(maxkey[0]), m1 = unkey(maxkey[1]), m2 = unkey(maxkey[2]);
  float w0=0.f, w1=0.f, w2=0.f, se0=0.f, se1=0.f, se2=0.f;
  for (int n = gw; n < N; n += nw){
    const float* ep = emb + (size_t)n*NVH;
    float x0 = expf(scores[n]       - m0);
    float x1 = expf(scores[N + n]   - m1);
    float x2 = expf(scores[2*N + n] - m2);
    w0 += ep[lane]*x0; w1 += ep[64+lane]*x1; w2 += ep[128+lane]*x2;
    se0 += x0; se1 += x1; se2 += x2;
  }
  shw[wv][lane]     = w0;
  shw[wv][64+lane]  = w1;
  shw[wv][128+lane] = w2;
  #pragma unroll
  for (int ofs = 32; ofs >= 1; ofs >>= 1){
    se0 += __shfl_xor(se0, ofs);
    se1 += __shfl_xor(se1, ofs);
    se2 += __shfl_xor(se2, ofs);
  }
  if (lane == 0){ shse[wv][0] = se0; shse[wv][1] = se1; shse[wv][2] = se2; }
  __syncthreads();
  if (t < NVH){
    float s = shw[0][t] + shw[1][t] + shw[2][t] + shw[3][t];
    atomicAdd(&wsum[t], s);
  } else if (t >= NVH && t < NVH+3){
    int v = t - NVH;
    float s = shse[0][v] + shse[1][v] + shse[2][v] + shse[3][v];
    atomicAdd(&sumexp[v], s);
  }
}

// ---- view attention (tiny) ----
__global__ __launch_bounds__(64) void k_view(const float* __restrict__ wsum, const float* __restrict__ sumexp,
                                             const float* __restrict__ va_w1, const float* __restrict__ va_b1,
                                             const float* __restrict__ va_w2, const float* __restrict__ va_b2,
                                             float* __restrict__ g, float* __restrict__ out_vw, int N){
  __shared__ float avg[NV][64];
  __shared__ float z1[NV][32];
  int t = threadIdx.x;
  if (t < 64){
    for (int v = 0; v < NV; ++v) avg[v][t] = wsum[v*64+t] / (sumexp[v] * (float)N);
  }
  __syncthreads();
  if (t < 32){
    for (int v = 0; v < NV; ++v){
      float a = va_b1[t];
      for (int h = 0; h < 64; ++h) a += avg[v][h]*va_w1[h*32 + t];
      z1[v][t] = tanhf(a);
    }
  }
  __syncthreads();
  if (t == 0){
    float vs[NV];
    for (int v = 0; v < NV; ++v){
      float a = va_b2[0];
      for (int j = 0; j < 32; ++j) a += z1[v][j]*va_w2[j];
      vs[v] = a;
    }
    float m = fmaxf(vs[0], fmaxf(vs[1], vs[2]));
    float e0 = expf(vs[0]-m), e1 = expf(vs[1]-m), e2 = expf(vs[2]-m);
    float inv = 1.f/(e0+e1+e2);
    float vw0 = e0*inv, vw1 = e1*inv, vw2 = e2*inv;
    out_vw[0] = vw0; out_vw[1] = vw1; out_vw[2] = vw2;
    g[0] = vw0/sumexp[0]; g[1] = vw1/sumexp[1]; g[2] = vw2/sumexp[2];
  }
}

// ---- fused output + classifier + log_softmax (wave per node) ----
__global__ __launch_bounds__(256) void k_fused(const float* __restrict__ emb, const float* __restrict__ scores,
                                               const unsigned* __restrict__ maxkey, const float* __restrict__ g,
                                               const float* __restrict__ cls_w, const float* __restrict__ cls_b,
                                               float* __restrict__ out, int N){
  int wid = (blockIdx.x*blockDim.x + threadIdx.x) >> 6;
  int lane = threadIdx.x & 63;
  if (wid >= N) return;
  int n = wid;
  float m0 = unkey(maxkey[0]), m1 = unkey(maxkey[1]), m2 = unkey(maxkey[2]);
  float w0 = expf(scores[n]       - m0)*g[0];
  float w1 = expf(scores[N + n]   - m1)*g[1];
  float w2 = expf(scores[2*N + n] - m2)*g[2];
  const float* ep = emb + (size_t)n*NVH;
  float fu = ep[lane]*w0 + ep[64+lane]*w1 + ep[128+lane]*w2;
  out[(size_t)2*N + (size_t)n*64 + lane] = fu;
  float c0 = fu*cls_w[lane*2 + 0];
  float c1 = fu*cls_w[lane*2 + 1];
  #pragma unroll
  for (int ofs = 32; ofs >= 1; ofs >>= 1){
    c0 += __shfl_xor(c0, ofs);
    c1 += __shfl_xor(c1, ofs);
  }
  if (lane == 0){
    float l0 = c0 + cls_b[0], l1 = c1 + cls_b[1];
    float m = fmaxf(l0, l1);
    float lse = m + logf(expf(l0-m) + expf(l1-m));
    out[(size_t)n*2]     = l0 - lse;
    out[(size_t)n*2 + 1] = l1 - lse;
  }
}

extern "C" void kernel_launch(void* const* d_in, const int* in_sizes, int n_in,
                              void* d_out, int out_size, void* d_ws, size_t ws_size,
                              hipStream_t stream){
  const float* x     = (const float*)d_in[0];
  const int*   ei    = (const int*)d_in[1];
  const float* Wv    = (const float*)d_in[2];
  const float* bv    = (const float*)d_in[3];
  const float* na_w  = (const float*)d_in[4];
  const float* na_b  = (const float*)d_in[5];
  const float* va_w1 = (const float*)d_in[6];
  const float* va_b1 = (const float*)d_in[7];
  const float* va_w2 = (const float*)d_in[8];
  const float* va_b2 = (const float*)d_in[9];
  const float* cls_w = (const float*)d_in[10];
  const float* cls_b = (const float*)d_in[11];
  int N = in_sizes[0] / (NV*DIMX);
  int E = in_sizes[1] / 2;
  float* out = (float*)d_out;

  char* wptr = (char*)d_ws;
  size_t off = 0;
  auto alloc = [&](size_t bytes){ void* p = wptr + off; off += (bytes + 255) & ~255ull; return p; };
  float*     hs       = (float*)alloc((size_t)N*NVH*4);   // fp32 h; aliased as emb after k_pack
  float*     emb      = hs;                                // k_agg writes here (hs fp32 dead by then)
  uint32*    h01      = (uint32*)alloc((size_t)N*64*4);
  ushort16*  h2       = (ushort16*)alloc((size_t)N*64*2);
  int*       csr      = (int*)alloc((size_t)E*4);
  int*       cnt      = (int*)alloc((size_t)N*4);
  int*       rowstart = (int*)alloc((size_t)(N+1)*4);
  int*       fill     = (int*)alloc((size_t)N*4);
  float*     dinv     = (float*)alloc((size_t)N*4);
  float*     scores   = (float*)alloc((size_t)3*N*4);
  unsigned*  maxkey   = (unsigned*)alloc(3*4);
  float*     sumexp   = (float*)alloc(3*4);
  float*     wsum     = (float*)alloc(192*4);
  float*     g        = (float*)alloc(3*4);
  int NB = (N + TS - 1) / TS;
  int*       bsum     = (int*)alloc((size_t)NB*4);
  int*       boff     = (int*)alloc((size_t)NB*4);

  hipMemsetAsync(cnt,    0, (size_t)N*4, stream);
  hipMemsetAsync(fill,   0, (size_t)N*4, stream);
  hipMemsetAsync(maxkey, 0, 3*4, stream);
  hipMemsetAsync(sumexp, 0, 3*4, stream);
  hipMemsetAsync(wsum,   0, 192*4, stream);

  k_count<<<(E+255)/256, 256, 0, stream>>>(ei, E, cnt);
  k_dinv <<<(N+255)/256, 256, 0, stream>>>(cnt, N, dinv);
  k_scanA<<<NB, 256, 0, stream>>>(cnt, N, bsum);
  k_scanB<<<1, 64, 0, stream>>>(bsum, NB, boff, rowstart, N);
  k_scanC<<<NB, 256, 0, stream>>>(cnt, N, boff, rowstart);
  k_fill <<<(E+255)/256, 256, 0, stream>>>(ei, E, rowstart, fill, csr);
  dim3 gh((N+127)/128, NV);
  k_h    <<<gh, 256, 0, stream>>>(x, Wv, dinv, hs, N);
  k_pack <<<(N*64+255)/256, 256, 0, stream>>>(hs, h01, h2, N*64);
  k_agg  <<<(N*64+255)/256, 256, 0, stream>>>(h01, h2, rowstart, csr, dinv, bv, na_w, na_b, emb, scores, N);
  dim3 gm((N+2047)/2048, NV);
  k_max  <<<gm, 256, 0, stream>>>(scores, N, maxkey);
  k_wsum <<<304, 256, 0, stream>>>(emb, scores, maxkey, wsum, sumexp, N);
  k_view <<<1, 64, 0, stream>>>(wsum, sumexp, va_w1, va_b1, va_w2, va_b2, g,
                                out + (size_t)2*N + (size_t)N*64, N);
  k_fused<<<(N*64+255)/256, 256, 0, stream>>>(emb, scores, maxkey, g, cls_w, cls_b, out, N);
}

// Round 4
// 222.135 us; speedup vs baseline: 2.2301x; 1.1890x over previous
//
#include <hip/hip_runtime.h>
#include <math.h>

#define NV 3
#define DIMX 128
#define HD 64
#define NVH 192
#define TS 1024

typedef unsigned int uint32;
typedef unsigned short ushort16;
typedef __attribute__((ext_vector_type(8))) short short8;
typedef __attribute__((ext_vector_type(4))) float f32x4;

__device__ __forceinline__ unsigned fkey(float f){
  unsigned b = __float_as_uint(f);
  return (b & 0x80000000u) ? ~b : (b | 0x80000000u);
}
__device__ __forceinline__ float unkey(unsigned k){
  return __uint_as_float((k & 0x80000000u) ? (k ^ 0x80000000u) : ~k);
}
__device__ __forceinline__ uint32 bf16rne(float f){
  uint32 u = __float_as_uint(f);
  return (u + 0x7fffu + ((u >> 16) & 1u)) >> 16;
}
__device__ __forceinline__ float bflo(uint32 p){ return __uint_as_float(p << 16); }
__device__ __forceinline__ float bfhi(uint32 p){ return __uint_as_float(p & 0xffff0000u); }
__device__ __forceinline__ float bfus(uint32 q){ return __uint_as_float(q << 16); }

// ---- CSR build ----
__global__ void k_count(const int* __restrict__ ei, int E, int* __restrict__ cnt){
  int e = blockIdx.x*blockDim.x + threadIdx.x;
  if (e < E){
    int d = ei[E + e];
    atomicAdd(&cnt[d], 1);
  }
}

__global__ void k_dinv(const int* __restrict__ cnt, int N, float* __restrict__ dinv){
  int n = blockIdx.x*blockDim.x + threadIdx.x;
  if (n < N) dinv[n] = rsqrtf((float)(cnt[n] + 1));   // +1 self-loop
}

// ---- 3-phase coalesced exclusive scan of cnt -> rowstart ----
__global__ __launch_bounds__(256) void k_scanA(const int* __restrict__ cnt, int N, int* __restrict__ bsum){
  __shared__ int sh[256];
  int b = blockIdx.x, t = threadIdx.x;
  int base = b*TS + t*4;
  int s = 0;
  #pragma unroll
  for (int k = 0; k < 4; ++k){ int i = base + k; if (i < N) s += cnt[i]; }
  sh[t] = s; __syncthreads();
  for (int ofs = 128; ofs >= 1; ofs >>= 1){
    if (t < ofs) sh[t] += sh[t+ofs];
    __syncthreads();
  }
  if (t == 0) bsum[b] = sh[0];
}

__global__ void k_scanB(const int* __restrict__ bsum, int NB, int* __restrict__ boff,
                        int* __restrict__ rowstart, int N){
  if (threadIdx.x == 0){
    int run = 0;
    for (int b = 0; b < NB; ++b){ boff[b] = run; run += bsum[b]; }
    rowstart[N] = run;
  }
}

__global__ __launch_bounds__(256) void k_scanC(const int* __restrict__ cnt, int N,
                                               const int* __restrict__ boff, int* __restrict__ rowstart){
  __shared__ int sh[256];
  int b = blockIdx.x, t = threadIdx.x;
  int base = b*TS + t*4;
  int c[4]; int s = 0;
  #pragma unroll
  for (int k = 0; k < 4; ++k){ int i = base + k; c[k] = (i < N) ? cnt[i] : 0; s += c[k]; }
  sh[t] = s; __syncthreads();
  for (int ofs = 1; ofs < 256; ofs <<= 1){
    int v = (t >= ofs) ? sh[t-ofs] : 0;
    __syncthreads();
    sh[t] += v;
    __syncthreads();
  }
  int run = boff[b] + sh[t] - s;
  #pragma unroll
  for (int k = 0; k < 4; ++k){ int i = base + k; if (i < N){ rowstart[i] = run; run += c[k]; } }
}

__global__ void k_fill(const int* __restrict__ ei, int E, const int* __restrict__ rowstart,
                       int* __restrict__ fill, int* __restrict__ csr){
  int e = blockIdx.x*blockDim.x + threadIdx.x;
  if (e < E){
    int s = ei[e], d = ei[E + e];
    int pos = rowstart[d] + atomicAdd(&fill[d], 1);
    csr[pos] = s;
  }
}

// ---- pack Wv into per-lane MFMA B-fragment order: Wb[v][c][s][lane] = 8 bf16 ----
__global__ __launch_bounds__(256) void k_wpack(const float* __restrict__ Wv, uint32* __restrict__ Wb){
  int t = blockIdx.x*blockDim.x + threadIdx.x;
  if (t >= 3072) return;
  int l = t & 63, s = (t >> 6) & 3, c = (t >> 8) & 3, v = t >> 10;
  int h = c*16 + (l & 15);
  int kbase = s*32 + (l >> 4)*8;
  const float* wp = Wv + v*8192 + h;
  uint32 o[4];
  #pragma unroll
  for (int jj = 0; jj < 4; ++jj){
    uint32 lo = bf16rne(wp[(kbase + 2*jj    )*64]);
    uint32 hi = bf16rne(wp[(kbase + 2*jj + 1)*64]);
    o[jj] = lo | (hi << 16);
  }
  Wb[t*4+0] = o[0]; Wb[t*4+1] = o[1]; Wb[t*4+2] = o[2]; Wb[t*4+3] = o[3];
}

// ---- MFMA linear transform fused with bf16 pack:
//      h01[n*64+h] = bf16(dinv[n]*h_v0) | bf16(dinv[n]*h_v1)<<16 ; h2 = bf16(dinv*h_v2)
__global__ __launch_bounds__(256) void k_h(const float* __restrict__ x, const uint32* __restrict__ Wb,
                                           const float* __restrict__ dinv,
                                           uint32* __restrict__ h01, ushort16* __restrict__ h2v, int N){
  int wave = (blockIdx.x*blockDim.x + threadIdx.x) >> 6;
  int lane = threadIdx.x & 63;
  int base = wave * 32;
  if (base >= N) return;
  int jrow = lane & 15;     // A-row / B-col / D-col selector
  int kq   = lane >> 4;     // k-quarter; D-row = kq*4 + reg

  // A row addresses (clamped for tail wave)
  int nl0 = base + jrow;        if (nl0 > N-1) nl0 = N-1;
  int nl1 = base + 16 + jrow;   if (nl1 > N-1) nl1 = N-1;
  const float* xr0 = x + (size_t)nl0*384 + kq*8;
  const float* xr1 = x + (size_t)nl1*384 + kq*8;
  const short8* WB = (const short8*)Wb;

  f32x4 acc0[2][4] = {};
  f32x4 acc1[2][4] = {};
  f32x4 acc2[2][4] = {};

  #pragma unroll
  for (int v = 0; v < NV; ++v){
    #pragma unroll
    for (int s = 0; s < 4; ++s){
      const float* p0 = xr0 + v*128 + s*32;
      const float* p1 = xr1 + v*128 + s*32;
      float4 f0 = *(const float4*)p0, g0 = *(const float4*)(p0+4);
      float4 f1 = *(const float4*)p1, g1 = *(const float4*)(p1+4);
      short8 a0, a1;
      a0[0]=(short)bf16rne(f0.x); a0[1]=(short)bf16rne(f0.y); a0[2]=(short)bf16rne(f0.z); a0[3]=(short)bf16rne(f0.w);
      a0[4]=(short)bf16rne(g0.x); a0[5]=(short)bf16rne(g0.y); a0[6]=(short)bf16rne(g0.z); a0[7]=(short)bf16rne(g0.w);
      a1[0]=(short)bf16rne(f1.x); a1[1]=(short)bf16rne(f1.y); a1[2]=(short)bf16rne(f1.z); a1[3]=(short)bf16rne(f1.w);
      a1[4]=(short)bf16rne(g1.x); a1[5]=(short)bf16rne(g1.y); a1[6]=(short)bf16rne(g1.z); a1[7]=(short)bf16rne(g1.w);
      #pragma unroll
      for (int c = 0; c < 4; ++c){
        short8 b = WB[(v*4 + c)*4*64 + s*64 + lane];
        if (v == 0){
          acc0[0][c] = __builtin_amdgcn_mfma_f32_16x16x32_bf16(a0, b, acc0[0][c], 0, 0, 0);
          acc0[1][c] = __builtin_amdgcn_mfma_f32_16x16x32_bf16(a1, b, acc0[1][c], 0, 0, 0);
        } else if (v == 1){
          acc1[0][c] = __builtin_amdgcn_mfma_f32_16x16x32_bf16(a0, b, acc1[0][c], 0, 0, 0);
          acc1[1][c] = __builtin_amdgcn_mfma_f32_16x16x32_bf16(a1, b, acc1[1][c], 0, 0, 0);
        } else {
          acc2[0][c] = __builtin_amdgcn_mfma_f32_16x16x32_bf16(a0, b, acc2[0][c], 0, 0, 0);
          acc2[1][c] = __builtin_amdgcn_mfma_f32_16x16x32_bf16(a1, b, acc2[1][c], 0, 0, 0);
        }
      }
    }
  }

  #pragma unroll
  for (int rt = 0; rt < 2; ++rt){
    #pragma unroll
    for (int r = 0; r < 4; ++r){
      int n = base + rt*16 + kq*4 + r;
      if (n < N){
        float dv = dinv[n];
        #pragma unroll
        for (int c = 0; c < 4; ++c){
          int h = c*16 + jrow;
          uint32 b0 = bf16rne(acc0[rt][c][r]*dv);
          uint32 b1 = bf16rne(acc1[rt][c][r]*dv);
          uint32 b2 = bf16rne(acc2[rt][c][r]*dv);
          h01[(size_t)n*64 + h] = b0 | (b1 << 16);
          h2v[(size_t)n*64 + h] = (ushort16)b2;
        }
      }
    }
  }
}

// ---- aggregation (wave per dst node, bf16 gather) + relu + node-attention scores ----
__global__ __launch_bounds__(256) void k_agg(const uint32* __restrict__ h01, const ushort16* __restrict__ h2,
                                             const int* __restrict__ rowstart, const int* __restrict__ csr,
                                             const float* __restrict__ dinv, const float* __restrict__ bv,
                                             const float* __restrict__ na_w, const float* __restrict__ na_b,
                                             ushort16* __restrict__ emb, float* __restrict__ scores, int N){
  int wid = (blockIdx.x*blockDim.x + threadIdx.x) >> 6;
  int lane = threadIdx.x & 63;
  if (wid >= N) return;
  int n = wid;
  uint32 ps = h01[(size_t)n*64 + lane];
  float a0 = bflo(ps), a1 = bfhi(ps), a2 = bfus(h2[(size_t)n*64 + lane]);
  int r0 = rowstart[n], r1 = rowstart[n+1];
  int i = r0;
  for (; i + 3 < r1; i += 4){
    int s0 = csr[i], s1 = csr[i+1], s2 = csr[i+2], s3 = csr[i+3];
    uint32 pa = h01[(size_t)s0*64 + lane];
    uint32 pb = h01[(size_t)s1*64 + lane];
    uint32 pc = h01[(size_t)s2*64 + lane];
    uint32 pd = h01[(size_t)s3*64 + lane];
    uint32 qa = h2[(size_t)s0*64 + lane];
    uint32 qb = h2[(size_t)s1*64 + lane];
    uint32 qc = h2[(size_t)s2*64 + lane];
    uint32 qd = h2[(size_t)s3*64 + lane];
    a0 += bflo(pa) + bflo(pb) + bflo(pc) + bflo(pd);
    a1 += bfhi(pa) + bfhi(pb) + bfhi(pc) + bfhi(pd);
    a2 += bfus(qa) + bfus(qb) + bfus(qc) + bfus(qd);
  }
  for (; i < r1; ++i){
    int s = csr[i];
    uint32 p = h01[(size_t)s*64 + lane];
    a0 += bflo(p); a1 += bfhi(p); a2 += bfus(h2[(size_t)s*64 + lane]);
  }
  float dv = dinv[n];
  float e0 = fmaxf(a0*dv + bv[lane],      0.f);
  float e1 = fmaxf(a1*dv + bv[64+lane],   0.f);
  float e2 = fmaxf(a2*dv + bv[128+lane],  0.f);
  ushort16* ep = emb + (size_t)n*NVH;
  ep[lane]     = (ushort16)bf16rne(e0);
  ep[64+lane]  = (ushort16)bf16rne(e1);
  ep[128+lane] = (ushort16)bf16rne(e2);
  float w = na_w[lane];
  float s0 = e0*w, s1 = e1*w, s2 = e2*w;
  #pragma unroll
  for (int ofs = 32; ofs >= 1; ofs >>= 1){
    s0 += __shfl_xor(s0, ofs);
    s1 += __shfl_xor(s1, ofs);
    s2 += __shfl_xor(s2, ofs);
  }
  if (lane == 0){
    float nb = na_b[0];
    scores[n] = s0 + nb; scores[N + n] = s1 + nb; scores[2*N + n] = s2 + nb;
  }
}

// ---- global max per view ----
__global__ void k_max(const float* __restrict__ scores, int N, unsigned* __restrict__ maxkey){
  __shared__ float sh[256];
  int v = blockIdx.y;
  const float* sp = scores + (size_t)v*N;
  int base = blockIdx.x*2048 + threadIdx.x;
  float m = -3.0e38f;
  #pragma unroll
  for (int k = 0; k < 8; ++k){
    int i = base + k*256;
    if (i < N) m = fmaxf(m, sp[i]);
  }
  sh[threadIdx.x] = m; __syncthreads();
  for (int ofs = 128; ofs >= 1; ofs >>= 1){
    if (threadIdx.x < ofs) sh[threadIdx.x] = fmaxf(sh[threadIdx.x], sh[threadIdx.x+ofs]);
    __syncthreads();
  }
  if (threadIdx.x == 0) atomicMax(&maxkey[v], fkey(sh[0]));
}

// ---- sum(exp) per view + weighted sum over nodes, hierarchical ----
__global__ __launch_bounds__(256) void k_wsum(const ushort16* __restrict__ emb, const float* __restrict__ scores,
                                              const unsigned* __restrict__ maxkey, float* __restrict__ wsum,
                                              float* __restrict__ sumexp, int N){
  __shared__ float shw[4][NVH];
  __shared__ float shse[4][4];
  int t = threadIdx.x;
  int lane = t & 63;
  int wv = t >> 6;
  int gw = (blockIdx.x*blockDim.x + t) >> 6;
  int nw = (gridDim.x*blockDim.x) >> 6;
  float m0 = unkey(maxkey[0]), m1 = unkey(maxkey[1]), m2 = unkey(maxkey[2]);
  float w0=0.f, w1=0.f, w2=0.f, se0=0.f, se1=0.f, se2=0.f;
  for (int n = gw; n < N; n += nw){
    const ushort16* ep = emb + (size_t)n*NVH;
    float x0 = expf(scores[n]       - m0);
    float x1 = expf(scores[N + n]   - m1);
    float x2 = expf(scores[2*N + n] - m2);
    w0 += bfus(ep[lane])*x0; w1 += bfus(ep[64+lane])*x1; w2 += bfus(ep[128+lane])*x2;
    se0 += x0; se1 += x1; se2 += x2;
  }
  shw[wv][lane]     = w0;
  shw[wv][64+lane]  = w1;
  shw[wv][128+lane] = w2;
  #pragma unroll
  for (int ofs = 32; ofs >= 1; ofs >>= 1){
    se0 += __shfl_xor(se0, ofs);
    se1 += __shfl_xor(se1, ofs);
    se2 += __shfl_xor(se2, ofs);
  }
  if (lane == 0){ shse[wv][0] = se0; shse[wv][1] = se1; shse[wv][2] = se2; }
  __syncthreads();
  if (t < NVH){
    float s = shw[0][t] + shw[1][t] + shw[2][t] + shw[3][t];
    atomicAdd(&wsum[t], s);
  } else if (t >= NVH && t < NVH+3){
    int v = t - NVH;
    float s = shse[0][v] + shse[1][v] + shse[2][v] + shse[3][v];
    atomicAdd(&sumexp[v], s);
  }
}

// ---- view attention (tiny) ----
__global__ __launch_bounds__(64) void k_view(const float* __restrict__ wsum, const float* __restrict__ sumexp,
                                             const float* __restrict__ va_w1, const float* __restrict__ va_b1,
                                             const float* __restrict__ va_w2, const float* __restrict__ va_b2,
                                             float* __restrict__ g, float* __restrict__ out_vw, int N){
  __shared__ float avg[NV][64];
  __shared__ float z1[NV][32];
  int t = threadIdx.x;
  if (t < 64){
    for (int v = 0; v < NV; ++v) avg[v][t] = wsum[v*64+t] / (sumexp[v] * (float)N);
  }
  __syncthreads();
  if (t < 32){
    for (int v = 0; v < NV; ++v){
      float a = va_b1[t];
      for (int h = 0; h < 64; ++h) a += avg[v][h]*va_w1[h*32 + t];
      z1[v][t] = tanhf(a);
    }
  }
  __syncthreads();
  if (t == 0){
    float vs[NV];
    for (int v = 0; v < NV; ++v){
      float a = va_b2[0];
      for (int j = 0; j < 32; ++j) a += z1[v][j]*va_w2[j];
      vs[v] = a;
    }
    float m = fmaxf(vs[0], fmaxf(vs[1], vs[2]));
    float e0 = expf(vs[0]-m), e1 = expf(vs[1]-m), e2 = expf(vs[2]-m);
    float inv = 1.f/(e0+e1+e2);
    float vw0 = e0*inv, vw1 = e1*inv, vw2 = e2*inv;
    out_vw[0] = vw0; out_vw[1] = vw1; out_vw[2] = vw2;
    g[0] = vw0/sumexp[0]; g[1] = vw1/sumexp[1]; g[2] = vw2/sumexp[2];
  }
}

// ---- fused output + classifier + log_softmax (wave per node) ----
__global__ __launch_bounds__(256) void k_fused(const ushort16* __restrict__ emb, const float* __restrict__ scores,
                                               const unsigned* __restrict__ maxkey, const float* __restrict__ g,
                                               const float* __restrict__ cls_w, const float* __restrict__ cls_b,
                                               float* __restrict__ out, int N){
  int wid = (blockIdx.x*blockDim.x + threadIdx.x) >> 6;
  int lane = threadIdx.x & 63;
  if (wid >= N) return;
  int n = wid;
  float m0 = unkey(maxkey[0]), m1 = unkey(maxkey[1]), m2 = unkey(maxkey[2]);
  float w0 = expf(scores[n]       - m0)*g[0];
  float w1 = expf(scores[N + n]   - m1)*g[1];
  float w2 = expf(scores[2*N + n] - m2)*g[2];
  const ushort16* ep = emb + (size_t)n*NVH;
  float fu = bfus(ep[lane])*w0 + bfus(ep[64+lane])*w1 + bfus(ep[128+lane])*w2;
  out[(size_t)2*N + (size_t)n*64 + lane] = fu;
  float c0 = fu*cls_w[lane*2 + 0];
  float c1 = fu*cls_w[lane*2 + 1];
  #pragma unroll
  for (int ofs = 32; ofs >= 1; ofs >>= 1){
    c0 += __shfl_xor(c0, ofs);
    c1 += __shfl_xor(c1, ofs);
  }
  if (lane == 0){
    float l0 = c0 + cls_b[0], l1 = c1 + cls_b[1];
    float m = fmaxf(l0, l1);
    float lse = m + logf(expf(l0-m) + expf(l1-m));
    out[(size_t)n*2]     = l0 - lse;
    out[(size_t)n*2 + 1] = l1 - lse;
  }
}

extern "C" void kernel_launch(void* const* d_in, const int* in_sizes, int n_in,
                              void* d_out, int out_size, void* d_ws, size_t ws_size,
                              hipStream_t stream){
  const float* x     = (const float*)d_in[0];
  const int*   ei    = (const int*)d_in[1];
  const float* Wv    = (const float*)d_in[2];
  const float* bv    = (const float*)d_in[3];
  const float* na_w  = (const float*)d_in[4];
  const float* na_b  = (const float*)d_in[5];
  const float* va_w1 = (const float*)d_in[6];
  const float* va_b1 = (const float*)d_in[7];
  const float* va_w2 = (const float*)d_in[8];
  const float* va_b2 = (const float*)d_in[9];
  const float* cls_w = (const float*)d_in[10];
  const float* cls_b = (const float*)d_in[11];
  int N = in_sizes[0] / (NV*DIMX);
  int E = in_sizes[1] / 2;
  float* out = (float*)d_out;

  char* wptr = (char*)d_ws;
  size_t off = 0;
  auto alloc = [&](size_t bytes){ void* p = wptr + off; off += (bytes + 255) & ~255ull; return p; };
  uint32*    h01      = (uint32*)alloc((size_t)N*64*4);
  ushort16*  h2       = (ushort16*)alloc((size_t)N*64*2);
  ushort16*  emb      = (ushort16*)alloc((size_t)N*NVH*2);
  int*       csr      = (int*)alloc((size_t)E*4);
  int*       cnt      = (int*)alloc((size_t)N*4);
  int*       rowstart = (int*)alloc((size_t)(N+1)*4);
  int*       fill     = (int*)alloc((size_t)N*4);
  float*     dinv     = (float*)alloc((size_t)N*4);
  float*     scores   = (float*)alloc((size_t)3*N*4);
  unsigned*  maxkey   = (unsigned*)alloc(3*4);
  float*     sumexp   = (float*)alloc(3*4);
  float*     wsum     = (float*)alloc(192*4);
  float*     g        = (float*)alloc(3*4);
  uint32*    Wb       = (uint32*)alloc(3072*16);
  int NB = (N + TS - 1) / TS;
  int*       bsum     = (int*)alloc((size_t)NB*4);
  int*       boff     = (int*)alloc((size_t)NB*4);

  hipMemsetAsync(cnt,    0, (size_t)N*4, stream);
  hipMemsetAsync(fill,   0, (size_t)N*4, stream);
  hipMemsetAsync(maxkey, 0, 3*4, stream);
  hipMemsetAsync(sumexp, 0, 3*4, stream);
  hipMemsetAsync(wsum,   0, 192*4, stream);

  k_count<<<(E+255)/256, 256, 0, stream>>>(ei, E, cnt);
  k_dinv <<<(N+255)/256, 256, 0, stream>>>(cnt, N, dinv);
  k_scanA<<<NB, 256, 0, stream>>>(cnt, N, bsum);
  k_scanB<<<1, 64, 0, stream>>>(bsum, NB, boff, rowstart, N);
  k_scanC<<<NB, 256, 0, stream>>>(cnt, N, boff, rowstart);
  k_fill <<<(E+255)/256, 256, 0, stream>>>(ei, E, rowstart, fill, csr);
  k_wpack<<<12, 256, 0, stream>>>(Wv, Wb);
  int waves = (N + 31) / 32;
  k_h    <<<(waves*64+255)/256, 256, 0, stream>>>(x, Wb, dinv, h01, h2, N);
  k_agg  <<<(N*64+255)/256, 256, 0, stream>>>(h01, h2, rowstart, csr, dinv, bv, na_w, na_b, emb, scores, N);
  dim3 gm((N+2047)/2048, NV);
  k_max  <<<gm, 256, 0, stream>>>(scores, N, maxkey);
  k_wsum <<<304, 256, 0, stream>>>(emb, scores, maxkey, wsum, sumexp, N);
  k_view <<<1, 64, 0, stream>>>(wsum, sumexp, va_w1, va_b1, va_w2, va_b2, g,
                                out + (size_t)2*N + (size_t)N*64, N);
  k_fused<<<(N*64+255)/256, 256, 0, stream>>>(emb, scores, maxkey, g, cls_w, cls_b, out, N);
}

// Round 5
// 168.220 us; speedup vs baseline: 2.9449x; 1.3205x over previous
//
#include <hip/hip_runtime.h>
#include <math.h>

#define NV 3
#define DIMX 128
#define HD 64
#define NVH 192
#define NBLK 256     // edge-partition blocks for hist/scatter
#define NBUK 128     // dst buckets of 512 nodes
#define BSH 9        // log2(512)

typedef unsigned int uint32;
typedef unsigned short ushort16;
typedef __attribute__((ext_vector_type(8))) short short8;
typedef __attribute__((ext_vector_type(4))) float f32x4;

__device__ __forceinline__ unsigned fkey(float f){
  unsigned b = __float_as_uint(f);
  return (b & 0x80000000u) ? ~b : (b | 0x80000000u);
}
__device__ __forceinline__ float unkey(unsigned k){
  return __uint_as_float((k & 0x80000000u) ? (k ^ 0x80000000u) : ~k);
}
__device__ __forceinline__ uint32 bf16rne(float f){
  uint32 u = __float_as_uint(f);
  return (u + 0x7fffu + ((u >> 16) & 1u)) >> 16;
}
__device__ __forceinline__ float bflo(uint32 p){ return __uint_as_float(p << 16); }
__device__ __forceinline__ float bfhi(uint32 p){ return __uint_as_float(p & 0xffff0000u); }
__device__ __forceinline__ float bfus(uint32 q){ return __uint_as_float(q << 16); }

// ---- CSR build: two-level counting sort, LDS atomics only ----
__global__ __launch_bounds__(256) void k_hist(const int* __restrict__ ei, int E, int EPB,
                                              int* __restrict__ histT){
  __shared__ int sh[NBUK];
  int t = threadIdx.x, b = blockIdx.x;
  if (t < NBUK) sh[t] = 0;
  __syncthreads();
  int e0 = b*EPB, e1 = min(e0 + EPB, E);
  for (int i = e0 + t; i < e1; i += 256){
    int d = ei[E + i];
    atomicAdd(&sh[d >> BSH], 1);
  }
  __syncthreads();
  if (t < NBUK) histT[t*NBLK + b] = sh[t];
}

// exclusive scan of histT[32768] in place (bucket-major, block-minor order)
__global__ __launch_bounds__(1024) void k_hscan(int* __restrict__ histT){
  __shared__ int sh[1024];
  int t = threadIdx.x;
  int lo = t*32;
  int vals[32]; int s = 0;
  #pragma unroll
  for (int k = 0; k < 32; ++k){ vals[k] = histT[lo+k]; s += vals[k]; }
  sh[t] = s; __syncthreads();
  for (int ofs = 1; ofs < 1024; ofs <<= 1){
    int v = (t >= ofs) ? sh[t-ofs] : 0;
    __syncthreads();
    sh[t] += v;
    __syncthreads();
  }
  int run = sh[t] - s;
  #pragma unroll
  for (int k = 0; k < 32; ++k){ histT[lo+k] = run; run += vals[k]; }
}

__global__ __launch_bounds__(256) void k_scatter(const int* __restrict__ ei, int E, int EPB,
                                                 const int* __restrict__ ofsT, int2* __restrict__ ebuf){
  __shared__ int cur[NBUK];
  int t = threadIdx.x, b = blockIdx.x;
  if (t < NBUK) cur[t] = ofsT[t*NBLK + b];
  __syncthreads();
  int e0 = b*EPB, e1 = min(e0 + EPB, E);
  for (int i = e0 + t; i < e1; i += 256){
    int s = ei[i], d = ei[E + i];
    int pos = atomicAdd(&cur[d >> BSH], 1);
    ebuf[pos] = make_int2(s, d);
  }
}

// one block per bucket: LDS hist + scan -> rowstart, dinv, csr
__global__ __launch_bounds__(512) void k_csr(const int2* __restrict__ ebuf, const int* __restrict__ ofsT,
                                             int E, int N, int* __restrict__ rowstart,
                                             float* __restrict__ dinv, int* __restrict__ csr){
  __shared__ int cnt[512];
  __shared__ int pre[512];
  int t = threadIdx.x, b = blockIdx.x;
  int estart = ofsT[b*NBLK];
  int eend   = ((b+1)*NBLK < NBUK*NBLK) ? ofsT[(b+1)*NBLK] : E;
  int n0 = b << BSH;
  int nn = min(512, N - n0);
  cnt[t] = 0;
  __syncthreads();
  for (int i = estart + t; i < eend; i += 512){
    int d = ebuf[i].y;
    atomicAdd(&cnt[d - n0], 1);
  }
  __syncthreads();
  int c = cnt[t];
  pre[t] = c;
  __syncthreads();
  for (int ofs = 1; ofs < 512; ofs <<= 1){
    int v = (t >= ofs) ? pre[t-ofs] : 0;
    __syncthreads();
    pre[t] += v;
    __syncthreads();
  }
  int excl = pre[t] - c;
  if (t < nn){
    rowstart[n0 + t] = estart + excl;
    dinv[n0 + t] = rsqrtf((float)(c + 1));
  }
  if (b == gridDim.x - 1 && t == 0) rowstart[N] = E;
  cnt[t] = estart + excl;   // cursor
  __syncthreads();
  for (int i = estart + t; i < eend; i += 512){
    int2 e = ebuf[i];
    int pos = atomicAdd(&cnt[e.y - n0], 1);
    csr[pos] = e.x;
  }
}

// ---- pack Wv into per-lane MFMA B-fragment order: Wb[v][c][s][lane] = 8 bf16 ----
__global__ __launch_bounds__(256) void k_wpack(const float* __restrict__ Wv, uint32* __restrict__ Wb){
  int t = blockIdx.x*blockDim.x + threadIdx.x;
  if (t >= 3072) return;
  int l = t & 63, s = (t >> 6) & 3, c = (t >> 8) & 3, v = t >> 10;
  int h = c*16 + (l & 15);
  int kbase = s*32 + (l >> 4)*8;
  const float* wp = Wv + v*8192 + h;
  uint32 o[4];
  #pragma unroll
  for (int jj = 0; jj < 4; ++jj){
    uint32 lo = bf16rne(wp[(kbase + 2*jj    )*64]);
    uint32 hi = bf16rne(wp[(kbase + 2*jj + 1)*64]);
    o[jj] = lo | (hi << 16);
  }
  Wb[t*4+0] = o[0]; Wb[t*4+1] = o[1]; Wb[t*4+2] = o[2]; Wb[t*4+3] = o[3];
}

// ---- MFMA linear transform fused with bf16 pack ----
__global__ __launch_bounds__(256) void k_h(const float* __restrict__ x, const uint32* __restrict__ Wb,
                                           const float* __restrict__ dinv,
                                           uint32* __restrict__ h01, ushort16* __restrict__ h2v, int N){
  int wave = (blockIdx.x*blockDim.x + threadIdx.x) >> 6;
  int lane = threadIdx.x & 63;
  int base = wave * 32;
  if (base >= N) return;
  int jrow = lane & 15;
  int kq   = lane >> 4;

  int nl0 = base + jrow;        if (nl0 > N-1) nl0 = N-1;
  int nl1 = base + 16 + jrow;   if (nl1 > N-1) nl1 = N-1;
  const float* xr0 = x + (size_t)nl0*384 + kq*8;
  const float* xr1 = x + (size_t)nl1*384 + kq*8;
  const short8* WB = (const short8*)Wb;

  f32x4 acc0[2][4] = {};
  f32x4 acc1[2][4] = {};
  f32x4 acc2[2][4] = {};

  #pragma unroll
  for (int v = 0; v < NV; ++v){
    #pragma unroll
    for (int s = 0; s < 4; ++s){
      const float* p0 = xr0 + v*128 + s*32;
      const float* p1 = xr1 + v*128 + s*32;
      float4 f0 = *(const float4*)p0, g0 = *(const float4*)(p0+4);
      float4 f1 = *(const float4*)p1, g1 = *(const float4*)(p1+4);
      short8 a0, a1;
      a0[0]=(short)bf16rne(f0.x); a0[1]=(short)bf16rne(f0.y); a0[2]=(short)bf16rne(f0.z); a0[3]=(short)bf16rne(f0.w);
      a0[4]=(short)bf16rne(g0.x); a0[5]=(short)bf16rne(g0.y); a0[6]=(short)bf16rne(g0.z); a0[7]=(short)bf16rne(g0.w);
      a1[0]=(short)bf16rne(f1.x); a1[1]=(short)bf16rne(f1.y); a1[2]=(short)bf16rne(f1.z); a1[3]=(short)bf16rne(f1.w);
      a1[4]=(short)bf16rne(g1.x); a1[5]=(short)bf16rne(g1.y); a1[6]=(short)bf16rne(g1.z); a1[7]=(short)bf16rne(g1.w);
      #pragma unroll
      for (int c = 0; c < 4; ++c){
        short8 b = WB[(v*4 + c)*4*64 + s*64 + lane];
        if (v == 0){
          acc0[0][c] = __builtin_amdgcn_mfma_f32_16x16x32_bf16(a0, b, acc0[0][c], 0, 0, 0);
          acc0[1][c] = __builtin_amdgcn_mfma_f32_16x16x32_bf16(a1, b, acc0[1][c], 0, 0, 0);
        } else if (v == 1){
          acc1[0][c] = __builtin_amdgcn_mfma_f32_16x16x32_bf16(a0, b, acc1[0][c], 0, 0, 0);
          acc1[1][c] = __builtin_amdgcn_mfma_f32_16x16x32_bf16(a1, b, acc1[1][c], 0, 0, 0);
        } else {
          acc2[0][c] = __builtin_amdgcn_mfma_f32_16x16x32_bf16(a0, b, acc2[0][c], 0, 0, 0);
          acc2[1][c] = __builtin_amdgcn_mfma_f32_16x16x32_bf16(a1, b, acc2[1][c], 0, 0, 0);
        }
      }
    }
  }

  #pragma unroll
  for (int rt = 0; rt < 2; ++rt){
    #pragma unroll
    for (int r = 0; r < 4; ++r){
      int n = base + rt*16 + kq*4 + r;
      if (n < N){
        float dv = dinv[n];
        #pragma unroll
        for (int c = 0; c < 4; ++c){
          int h = c*16 + jrow;
          uint32 b0 = bf16rne(acc0[rt][c][r]*dv);
          uint32 b1 = bf16rne(acc1[rt][c][r]*dv);
          uint32 b2 = bf16rne(acc2[rt][c][r]*dv);
          h01[(size_t)n*64 + h] = b0 | (b1 << 16);
          h2v[(size_t)n*64 + h] = (ushort16)b2;
        }
      }
    }
  }
}

// ---- aggregation (wave per dst node, bf16 gather) + relu + node-attention scores ----
__global__ __launch_bounds__(256) void k_agg(const uint32* __restrict__ h01, const ushort16* __restrict__ h2,
                                             const int* __restrict__ rowstart, const int* __restrict__ csr,
                                             const float* __restrict__ dinv, const float* __restrict__ bv,
                                             const float* __restrict__ na_w, const float* __restrict__ na_b,
                                             ushort16* __restrict__ emb, float* __restrict__ scores, int N){
  int wid = (blockIdx.x*blockDim.x + threadIdx.x) >> 6;
  int lane = threadIdx.x & 63;
  if (wid >= N) return;
  int n = wid;
  uint32 ps = h01[(size_t)n*64 + lane];
  float a0 = bflo(ps), a1 = bfhi(ps), a2 = bfus(h2[(size_t)n*64 + lane]);
  int r0 = rowstart[n], r1 = rowstart[n+1];
  int i = r0;
  for (; i + 3 < r1; i += 4){
    int s0 = csr[i], s1 = csr[i+1], s2 = csr[i+2], s3 = csr[i+3];
    uint32 pa = h01[(size_t)s0*64 + lane];
    uint32 pb = h01[(size_t)s1*64 + lane];
    uint32 pc = h01[(size_t)s2*64 + lane];
    uint32 pd = h01[(size_t)s3*64 + lane];
    uint32 qa = h2[(size_t)s0*64 + lane];
    uint32 qb = h2[(size_t)s1*64 + lane];
    uint32 qc = h2[(size_t)s2*64 + lane];
    uint32 qd = h2[(size_t)s3*64 + lane];
    a0 += bflo(pa) + bflo(pb) + bflo(pc) + bflo(pd);
    a1 += bfhi(pa) + bfhi(pb) + bfhi(pc) + bfhi(pd);
    a2 += bfus(qa) + bfus(qb) + bfus(qc) + bfus(qd);
  }
  for (; i < r1; ++i){
    int s = csr[i];
    uint32 p = h01[(size_t)s*64 + lane];
    a0 += bflo(p); a1 += bfhi(p); a2 += bfus(h2[(size_t)s*64 + lane]);
  }
  float dv = dinv[n];
  float e0 = fmaxf(a0*dv + bv[lane],      0.f);
  float e1 = fmaxf(a1*dv + bv[64+lane],   0.f);
  float e2 = fmaxf(a2*dv + bv[128+lane],  0.f);
  ushort16* ep = emb + (size_t)n*NVH;
  ep[lane]     = (ushort16)bf16rne(e0);
  ep[64+lane]  = (ushort16)bf16rne(e1);
  ep[128+lane] = (ushort16)bf16rne(e2);
  float w = na_w[lane];
  float s0 = e0*w, s1 = e1*w, s2 = e2*w;
  #pragma unroll
  for (int ofs = 32; ofs >= 1; ofs >>= 1){
    s0 += __shfl_xor(s0, ofs);
    s1 += __shfl_xor(s1, ofs);
    s2 += __shfl_xor(s2, ofs);
  }
  if (lane == 0){
    float nb = na_b[0];
    scores[n] = s0 + nb; scores[N + n] = s1 + nb; scores[2*N + n] = s2 + nb;
  }
}

// ---- global max per view ----
__global__ void k_max(const float* __restrict__ scores, int N, unsigned* __restrict__ maxkey){
  __shared__ float sh[256];
  int v = blockIdx.y;
  const float* sp = scores + (size_t)v*N;
  int base = blockIdx.x*2048 + threadIdx.x;
  float m = -3.0e38f;
  #pragma unroll
  for (int k = 0; k < 8; ++k){
    int i = base + k*256;
    if (i < N) m = fmaxf(m, sp[i]);
  }
  sh[threadIdx.x] = m; __syncthreads();
  for (int ofs = 128; ofs >= 1; ofs >>= 1){
    if (threadIdx.x < ofs) sh[threadIdx.x] = fmaxf(sh[threadIdx.x], sh[threadIdx.x+ofs]);
    __syncthreads();
  }
  if (threadIdx.x == 0) atomicMax(&maxkey[v], fkey(sh[0]));
}

// ---- sum(exp) per view + weighted sum over nodes, hierarchical ----
__global__ __launch_bounds__(256) void k_wsum(const ushort16* __restrict__ emb, const float* __restrict__ scores,
                                              const unsigned* __restrict__ maxkey, float* __restrict__ wsum,
                                              float* __restrict__ sumexp, int N){
  __shared__ float shw[4][NVH];
  __shared__ float shse[4][4];
  int t = threadIdx.x;
  int lane = t & 63;
  int wv = t >> 6;
  int gw = (blockIdx.x*blockDim.x + t) >> 6;
  int nw = (gridDim.x*blockDim.x) >> 6;
  float m0 = unkey(maxkey[0]), m1 = unkey(maxkey[1]), m2 = unkey(maxkey[2]);
  float w0=0.f, w1=0.f, w2=0.f, se0=0.f, se1=0.f, se2=0.f;
  for (int n = gw; n < N; n += nw){
    const ushort16* ep = emb + (size_t)n*NVH;
    float x0 = expf(scores[n]       - m0);
    float x1 = expf(scores[N + n]   - m1);
    float x2 = expf(scores[2*N + n] - m2);
    w0 += bfus(ep[lane])*x0; w1 += bfus(ep[64+lane])*x1; w2 += bfus(ep[128+lane])*x2;
    se0 += x0; se1 += x1; se2 += x2;
  }
  shw[wv][lane]     = w0;
  shw[wv][64+lane]  = w1;
  shw[wv][128+lane] = w2;
  #pragma unroll
  for (int ofs = 32; ofs >= 1; ofs >>= 1){
    se0 += __shfl_xor(se0, ofs);
    se1 += __shfl_xor(se1, ofs);
    se2 += __shfl_xor(se2, ofs);
  }
  if (lane == 0){ shse[wv][0] = se0; shse[wv][1] = se1; shse[wv][2] = se2; }
  __syncthreads();
  if (t < NVH){
    float s = shw[0][t] + shw[1][t] + shw[2][t] + shw[3][t];
    atomicAdd(&wsum[t], s);
  } else if (t >= NVH && t < NVH+3){
    int v = t - NVH;
    float s = shse[0][v] + shse[1][v] + shse[2][v] + shse[3][v];
    atomicAdd(&sumexp[v], s);
  }
}

// ---- view attention (tiny) ----
__global__ __launch_bounds__(64) void k_view(const float* __restrict__ wsum, const float* __restrict__ sumexp,
                                             const float* __restrict__ va_w1, const float* __restrict__ va_b1,
                                             const float* __restrict__ va_w2, const float* __restrict__ va_b2,
                                             float* __restrict__ g, float* __restrict__ out_vw, int N){
  __shared__ float avg[NV][64];
  __shared__ float z1[NV][32];
  int t = threadIdx.x;
  if (t < 64){
    for (int v = 0; v < NV; ++v) avg[v][t] = wsum[v*64+t] / (sumexp[v] * (float)N);
  }
  __syncthreads();
  if (t < 32){
    for (int v = 0; v < NV; ++v){
      float a = va_b1[t];
      for (int h = 0; h < 64; ++h) a += avg[v][h]*va_w1[h*32 + t];
      z1[v][t] = tanhf(a);
    }
  }
  __syncthreads();
  if (t == 0){
    float vs[NV];
    for (int v = 0; v < NV; ++v){
      float a = va_b2[0];
      for (int j = 0; j < 32; ++j) a += z1[v][j]*va_w2[j];
      vs[v] = a;
    }
    float m = fmaxf(vs[0], fmaxf(vs[1], vs[2]));
    float e0 = expf(vs[0]-m), e1 = expf(vs[1]-m), e2 = expf(vs[2]-m);
    float inv = 1.f/(e0+e1+e2);
    float vw0 = e0*inv, vw1 = e1*inv, vw2 = e2*inv;
    out_vw[0] = vw0; out_vw[1] = vw1; out_vw[2] = vw2;
    g[0] = vw0/sumexp[0]; g[1] = vw1/sumexp[1]; g[2] = vw2/sumexp[2];
  }
}

// ---- fused output + classifier + log_softmax (wave per node) ----
__global__ __launch_bounds__(256) void k_fused(const ushort16* __restrict__ emb, const float* __restrict__ scores,
                                               const unsigned* __restrict__ maxkey, const float* __restrict__ g,
                                               const float* __restrict__ cls_w, const float* __restrict__ cls_b,
                                               float* __restrict__ out, int N){
  int wid = (blockIdx.x*blockDim.x + threadIdx.x) >> 6;
  int lane = threadIdx.x & 63;
  if (wid >= N) return;
  int n = wid;
  float m0 = unkey(maxkey[0]), m1 = unkey(maxkey[1]), m2 = unkey(maxkey[2]);
  float w0 = expf(scores[n]       - m0)*g[0];
  float w1 = expf(scores[N + n]   - m1)*g[1];
  float w2 = expf(scores[2*N + n] - m2)*g[2];
  const ushort16* ep = emb + (size_t)n*NVH;
  float fu = bfus(ep[lane])*w0 + bfus(ep[64+lane])*w1 + bfus(ep[128+lane])*w2;
  out[(size_t)2*N + (size_t)n*64 + lane] = fu;
  float c0 = fu*cls_w[lane*2 + 0];
  float c1 = fu*cls_w[lane*2 + 1];
  #pragma unroll
  for (int ofs = 32; ofs >= 1; ofs >>= 1){
    c0 += __shfl_xor(c0, ofs);
    c1 += __shfl_xor(c1, ofs);
  }
  if (lane == 0){
    float l0 = c0 + cls_b[0], l1 = c1 + cls_b[1];
    float m = fmaxf(l0, l1);
    float lse = m + logf(expf(l0-m) + expf(l1-m));
    out[(size_t)n*2]     = l0 - lse;
    out[(size_t)n*2 + 1] = l1 - lse;
  }
}

extern "C" void kernel_launch(void* const* d_in, const int* in_sizes, int n_in,
                              void* d_out, int out_size, void* d_ws, size_t ws_size,
                              hipStream_t stream){
  const float* x     = (const float*)d_in[0];
  const int*   ei    = (const int*)d_in[1];
  const float* Wv    = (const float*)d_in[2];
  const float* bv    = (const float*)d_in[3];
  const float* na_w  = (const float*)d_in[4];
  const float* na_b  = (const float*)d_in[5];
  const float* va_w1 = (const float*)d_in[6];
  const float* va_b1 = (const float*)d_in[7];
  const float* va_w2 = (const float*)d_in[8];
  const float* va_b2 = (const float*)d_in[9];
  const float* cls_w = (const float*)d_in[10];
  const float* cls_b = (const float*)d_in[11];
  int N = in_sizes[0] / (NV*DIMX);
  int E = in_sizes[1] / 2;
  float* out = (float*)d_out;

  char* wptr = (char*)d_ws;
  size_t off = 0;
  auto alloc = [&](size_t bytes){ void* p = wptr + off; off += (bytes + 255) & ~255ull; return p; };
  uint32*    h01      = (uint32*)alloc((size_t)N*64*4);
  ushort16*  h2       = (ushort16*)alloc((size_t)N*64*2);
  ushort16*  emb      = (ushort16*)alloc((size_t)N*NVH*2);
  int*       csr      = (int*)alloc((size_t)E*4);
  int2*      ebuf     = (int2*)alloc((size_t)E*8);
  int*       histT    = (int*)alloc((size_t)NBUK*NBLK*4);
  int*       rowstart = (int*)alloc((size_t)(N+1)*4);
  float*     dinv     = (float*)alloc((size_t)N*4);
  float*     scores   = (float*)alloc((size_t)3*N*4);
  unsigned*  maxkey   = (unsigned*)alloc(3*4);
  float*     sumexp   = (float*)alloc(3*4);
  float*     wsum     = (float*)alloc(192*4);
  float*     g        = (float*)alloc(3*4);
  uint32*    Wb       = (uint32*)alloc(3072*16);

  hipMemsetAsync(maxkey, 0, 3*4, stream);
  hipMemsetAsync(sumexp, 0, 3*4, stream);
  hipMemsetAsync(wsum,   0, 192*4, stream);

  int EPB = (E + NBLK - 1) / NBLK;
  int nbuck = (N + 511) >> BSH;
  k_hist   <<<NBLK, 256, 0, stream>>>(ei, E, EPB, histT);
  k_hscan  <<<1, 1024, 0, stream>>>(histT);
  k_scatter<<<NBLK, 256, 0, stream>>>(ei, E, EPB, histT, ebuf);
  k_csr    <<<nbuck, 512, 0, stream>>>(ebuf, histT, E, N, rowstart, dinv, csr);
  k_wpack  <<<12, 256, 0, stream>>>(Wv, Wb);
  int waves = (N + 31) / 32;
  k_h      <<<(waves*64+255)/256, 256, 0, stream>>>(x, Wb, dinv, h01, h2, N);
  k_agg    <<<(N*64+255)/256, 256, 0, stream>>>(h01, h2, rowstart, csr, dinv, bv, na_w, na_b, emb, scores, N);
  dim3 gm((N+2047)/2048, NV);
  k_max    <<<gm, 256, 0, stream>>>(scores, N, maxkey);
  k_wsum   <<<304, 256, 0, stream>>>(emb, scores, maxkey, wsum, sumexp, N);
  k_view   <<<1, 64, 0, stream>>>(wsum, sumexp, va_w1, va_b1, va_w2, va_b2, g,
                                  out + (size_t)2*N + (size_t)N*64, N);
  k_fused  <<<(N*64+255)/256, 256, 0, stream>>>(emb, scores, maxkey, g, cls_w, cls_b, out, N);
}